// Round 15
// baseline (504.659 us; speedup 1.0000x reference)
//
#include <hip/hip_runtime.h>
#include <stdint.h>

#define N_NODES 20000
#define N_EDGES 320000

typedef __attribute__((ext_vector_type(8)))  __bf16        bf16x8;
typedef __attribute__((ext_vector_type(16))) float         f32x16;
typedef __attribute__((ext_vector_type(4)))  float         f32x4v;
typedef __attribute__((ext_vector_type(4)))  uint32_t      u32x4;
typedef __attribute__((ext_vector_type(8)))  unsigned short us8;
typedef __attribute__((ext_vector_type(2)))  unsigned short us2;

static __device__ __forceinline__ unsigned short cvt_bf16(float f) {
  uint32_t u = __builtin_bit_cast(uint32_t, f);
  u = (u + 0x7fffu + ((u >> 16) & 1u)) >> 16;
  return (unsigned short)u;
}
static __device__ __forceinline__ float cvt_f32(unsigned short h) {
  uint32_t u = ((uint32_t)h) << 16;
  return __builtin_bit_cast(float, u);
}

// async global->LDS, 16B per lane; LDS dest = wave-uniform base (HW adds lane*16)
static __device__ __forceinline__ void gll16(const void* g, void* l) {
  __builtin_amdgcn_global_load_lds(
      (const __attribute__((address_space(1))) unsigned int*)g,
      (__attribute__((address_space(3))) unsigned int*)l, 16, 0, 0);
}

// literal-folded counted vmcnt wait
#define WAITV(n) do { \
  if ((n) == 0)       asm volatile("s_waitcnt vmcnt(0)"  ::: "memory"); \
  else if ((n) == 4)  asm volatile("s_waitcnt vmcnt(4)"  ::: "memory"); \
  else if ((n) == 8)  asm volatile("s_waitcnt vmcnt(8)"  ::: "memory"); \
  else if ((n) == 12) asm volatile("s_waitcnt vmcnt(12)" ::: "memory"); \
  else if ((n) == 16) asm volatile("s_waitcnt vmcnt(16)" ::: "memory"); \
  else                asm volatile("s_waitcnt vmcnt(24)" ::: "memory"); \
} while (0)

// ---------------------------------------------------------------------------
// pack_w: natural k-order fragments (verified R1-R13).
// out[((ks*(N/32)+nt)*64+ln)*8+e] = W[ks*16+(ln>>5)*8+e][nt*32+(ln&31)]
// ---------------------------------------------------------------------------
__global__ void pack_w(const float* __restrict__ W, unsigned short* __restrict__ out,
                       int K, int Ncols) {
  int idx = blockIdx.x * 256 + threadIdx.x;
  int total = K * Ncols;
  if (idx >= total) return;
  int e    = idx & 7;
  int lane = (idx >> 3) & 63;
  int t    = idx >> 9;
  int ntiles = Ncols >> 5;
  int nt = t % ntiles;
  int ks = t / ntiles;
  int k = ks * 16 + (lane >> 5) * 8 + e;
  int c = nt * 32 + (lane & 31);
  out[idx] = cvt_bf16(W[(size_t)k * Ncols + c]);
}

// ---------------------------------------------------------------------------
// pack_w2: sigma k-order for the register-resident H handoff (verified R6-R13).
// sigma(ks,g,e) = ks*16 + g*4 + (e&3) + 8*(e>>2)
// ---------------------------------------------------------------------------
__global__ void pack_w2(const float* __restrict__ W, unsigned short* __restrict__ out) {
  int idx = blockIdx.x * 256 + threadIdx.x;     // 32768 total
  if (idx >= 32768) return;
  int e    = idx & 7;
  int lane = (idx >> 3) & 63;
  int t    = idx >> 9;          // frag = ks*4 + nt
  int nt = t & 3, ks = t >> 2;
  int k = ks * 16 + ((lane >> 5) << 2) + (e & 3) + ((e >> 2) << 3);
  int c = nt * 32 + (lane & 31);
  out[idx] = cvt_bf16(W[(size_t)k * 128 + c]);
}

// ---------------------------------------------------------------------------
// CSR build; fill_k also emits sorted senders/receivers + pos (edge->slot).
// ---------------------------------------------------------------------------
__global__ void hist_k(const int* __restrict__ recv, int* __restrict__ cnt, int n) {
  int i = blockIdx.x * 256 + threadIdx.x;
  if (i < n) atomicAdd(&cnt[recv[i]], 1);
}

__global__ void scan_k(const int* __restrict__ cnt, int* __restrict__ off,
                       int* __restrict__ cursor, int n) {
  __shared__ int part[1024];
  int t = threadIdx.x;
  int chunk = (n + 1023) / 1024;
  int base = t * chunk;
  int s = 0;
  for (int i = 0; i < chunk; ++i) { int idx = base + i; if (idx < n) s += cnt[idx]; }
  part[t] = s;
  __syncthreads();
  for (int d = 1; d < 1024; d <<= 1) {
    int v = (t >= d) ? part[t - d] : 0;
    __syncthreads();
    part[t] += v;
    __syncthreads();
  }
  int prefix = (t > 0) ? part[t - 1] : 0;
  for (int i = 0; i < chunk; ++i) {
    int idx = base + i;
    if (idx < n) { off[idx] = prefix; cursor[idx] = prefix; prefix += cnt[idx]; }
  }
  if (t == 1023) off[n] = part[1023];
}

__global__ void fill_k(const int* __restrict__ send, const int* __restrict__ recv,
                       int* __restrict__ cursor, int* __restrict__ pos,
                       int* __restrict__ ssend, int* __restrict__ srecv, int n) {
  int i = blockIdx.x * 256 + threadIdx.x;
  if (i < n) {
    int p = atomicAdd(&cursor[recv[i]], 1);
    pos[i] = p;
    ssend[p] = send[i];
    srecv[p] = recv[i];
  }
}

// agg[n][:] = sum of CONTIGUOUS sorted e rows [off[n], off[n+1]) — streaming.
__global__ void agg_k(const unsigned short* __restrict__ eb, const int* __restrict__ off,
                      unsigned short* __restrict__ aggb, int n) {
  int node = blockIdx.x * 4 + (threadIdx.x >> 6);
  if (node >= n) return;
  int lane = threadIdx.x & 63;
  float a0 = 0.f, a1 = 0.f;
  int s = off[node], t = off[node + 1];
  for (int q = s; q < t; ++q) {
    us2 v = *(const us2*)(eb + (size_t)q * 128 + lane * 2);
    a0 += cvt_f32(v[0]);
    a1 += cvt_f32(v[1]);
  }
  us2 r; r[0] = cvt_bf16(a0); r[1] = cvt_bf16(a1);
  *(us2*)(aggb + (size_t)node * 128 + lane * 2) = r;
}

// ---------------------------------------------------------------------------
// precompute_k: XP[n] = [x[n]*W1a ; x[n]*W1b] in acc-fragment order (bf16).
// XP[((n*2+m)*2+g)*128 + t*16 + reg]  <=>  hidden t*32+(reg&3)+8*(reg>>2)+4g.
// Pd1 k-steps 0-3 = W1a (x[senders] rows), 4-7 = W1b (x[receivers] rows).
// ---------------------------------------------------------------------------
__global__ __launch_bounds__(256, 2)
void precompute_k(const unsigned short* __restrict__ xb,
                  const unsigned short* __restrict__ Pd1,
                  unsigned short* __restrict__ XP, int nrows) {
  __shared__ __align__(16) unsigned char lds[65536];
  const int tid = threadIdx.x, lane = tid & 63, wid = tid >> 6;
  const int g = lane >> 5, l31 = lane & 31;
  const int rowBlock = blockIdx.x << 7;
  int grow = rowBlock + wid * 32 + l31;
  if (grow >= nrows) grow = nrows - 1;
  const unsigned short* pX = xb + (size_t)grow * 128;
  const unsigned char* Pb = (const unsigned char*)Pd1;

  auto STG = [&](int s, int buf) {
    unsigned char* bW = lds + buf * 16384;
#pragma unroll
    for (int c = 0; c < 4; ++c)
      gll16(Pb + (size_t)s * 16384 + c * 4096 + tid * 16, bW + c * 4096 + wid * 1024);
  };

  us8 rows[4][2];
#pragma unroll
  for (int s = 0; s < 4; ++s) {
    rows[s][0] = *(const us8*)(pX + s * 32 + g * 8);
    rows[s][1] = *(const us8*)(pX + s * 32 + 16 + g * 8);
  }
  STG(0, 0); STG(1, 1); STG(2, 2); STG(3, 3);

  f32x16 acc[8];
  auto ZERO = [&]() {
#pragma unroll
    for (int t = 0; t < 8; ++t)
#pragma unroll
      for (int k = 0; k < 16; ++k) acc[t][k] = 0.0f;
  };
  auto COMP = [&](int buf, bf16x8 b0v, bf16x8 b1v) {
    const unsigned char* bW = lds + buf * 16384;
#pragma unroll
    for (int kc = 0; kc < 2; ++kc) {
      const bf16x8 bv = kc ? b1v : b0v;
#pragma unroll
      for (int nt = 0; nt < 8; ++nt) {
        bf16x8 av = __builtin_bit_cast(bf16x8,
            *(const us8*)(bW + (kc * 8 + nt) * 1024 + lane * 16));
        acc[nt] = __builtin_amdgcn_mfma_f32_32x32x16_bf16(av, bv, acc[nt], 0, 0, 0);
      }
    }
  };
  auto WOUT = [&](int m) {
    unsigned short* dst = XP + (((size_t)grow * 2 + m) * 2 + g) * 128;
#pragma unroll
    for (int t = 0; t < 8; ++t) {
      us8 h0, h1;
#pragma unroll
      for (int j = 0; j < 8; ++j) { h0[j] = cvt_bf16(acc[t][j]); h1[j] = cvt_bf16(acc[t][8 + j]); }
      *(us8*)(dst + t * 16) = h0;
      *(us8*)(dst + t * 16 + 8) = h1;
    }
  };

  ZERO();
  WAITV(0);
  asm volatile("s_barrier" ::: "memory");
#pragma unroll
  for (int s = 0; s < 4; ++s)
    COMP(s, __builtin_bit_cast(bf16x8, rows[s][0]), __builtin_bit_cast(bf16x8, rows[s][1]));
  asm volatile("s_waitcnt lgkmcnt(0)" ::: "memory");
  asm volatile("s_barrier" ::: "memory");
  STG(4, 0); STG(5, 1); STG(6, 2); STG(7, 3);
  WOUT(0);
  ZERO();
  WAITV(0);
  asm volatile("s_barrier" ::: "memory");
#pragma unroll
  for (int s = 0; s < 4; ++s)
    COMP(s, __builtin_bit_cast(bf16x8, rows[s][0]), __builtin_bit_cast(bf16x8, rows[s][1]));
  WOUT(1);
}

// ---------------------------------------------------------------------------
// Fused 2-layer MLP (verified structure R6-R13).
//  MODE 0: A = srcf f32 (KIN=128), optional perm'd output (embed-edge).
//  MODE 1: edge-model, SORTED order, KIN=128 (e*W1c only); x-contributions
//          folded from XP via register gathers with STRICT fold-before-reload
//          slot discipline (R14 bug: XPLOAD(2/3) clobbered unfolded slots).
//  MODE 2: A = [x, agg] bf16 (KIN=256) + fused pool.
// ---------------------------------------------------------------------------
template <int KIN, int MODE, int POOL>
__global__ __launch_bounds__(256, 2)
void mlp_kernel(const float* __restrict__ srcf,
                const unsigned short* __restrict__ xb,
                const unsigned short* __restrict__ ebuf,
                const unsigned short* __restrict__ xpb,
                const int* __restrict__ senders,
                const int* __restrict__ receivers,
                const int* __restrict__ perm,
                const unsigned short* __restrict__ P1,
                const float* __restrict__ b1,
                const unsigned short* __restrict__ P2,
                const float* __restrict__ b2,
                unsigned short* __restrict__ dst,
                float* __restrict__ pool_out,
                int nrows) {
  constexpr int NS1 = KIN / 32;
  constexpr int NP  = NS1 / 2;
  __shared__ __align__(16) unsigned char lds[65536];   // 4 x 16KB rotation

  const int tid  = threadIdx.x;
  const int lane = tid & 63;
  const int wid  = tid >> 6;
  const int g    = lane >> 5;
  const int l31  = lane & 31;
  const int rowBlock = blockIdx.x << 7;

  const unsigned char* P1b = (const unsigned char*)P1;
  const unsigned char* P2b = (const unsigned char*)P2;

  int grow = rowBlock + wid * 32 + l31;
  if (grow >= nrows) grow = nrows - 1;

  const unsigned short *pE = nullptr, *pX = nullptr, *pAg = nullptr;
  const unsigned short *pXa = nullptr, *pXb = nullptr;
  const float* fb = nullptr;
  if constexpr (MODE == 0) {
    fb = srcf + (size_t)grow * KIN;
  } else if constexpr (MODE == 1) {
    pE  = ebuf + (size_t)grow * 128;                       // sorted, contiguous
    pXa = xpb + (size_t)senders[grow] * 512 + g * 128;     // XP[s][a][g]
    pXb = xpb + (size_t)receivers[grow] * 512 + 256 + g * 128;  // XP[r][b][g]
  } else {
    pX  = xb + (size_t)grow * 128;
    pAg = xpb + (size_t)grow * 128;                        // aggb in xpb slot
  }

  auto STG1 = [&](int s) {
    unsigned char* bW = lds + (s & 3) * 16384;
#pragma unroll
    for (int c = 0; c < 4; ++c)
      gll16(P1b + (size_t)s * 16384 + c * 4096 + tid * 16,
            bW + c * 4096 + wid * 1024);
  };
  auto STG2 = [&](int c) {
    unsigned char* bW = lds + ((c + NS1) & 3) * 16384;
#pragma unroll
    for (int q = 0; q < 4; ++q)
      gll16(P2b + (size_t)c * 16384 + q * 4096 + tid * 16,
            bW + q * 4096 + wid * 1024);
  };

  auto LROW = [&](int s, us8* o) {
    const unsigned short* p;
    int ko;
    if constexpr (MODE == 1) { p = pE; ko = s * 32; }
    else { const int k0s = s * 32; p = (k0s >> 7) ? pAg : pX; ko = k0s & 127; }
    o[0] = *(const us8*)(p + ko + g * 8);
    o[1] = *(const us8*)(p + ko + 16 + g * 8);
  };
  auto LROWF = [&](int s, f32x4v* rf) {
    const float* p = fb + s * 32 + g * 8;
    rf[0] = *(const f32x4v*)(p);
    rf[1] = *(const f32x4v*)(p + 4);
    rf[2] = *(const f32x4v*)(p + 16);
    rf[3] = *(const f32x4v*)(p + 20);
  };
  auto MKBR = [&](const f32x4v* rf, bf16x8& b0v, bf16x8& b1v) {
    us8 h0, h1;
#pragma unroll
    for (int e = 0; e < 4; ++e) {
      h0[e] = cvt_bf16(rf[0][e]); h0[4 + e] = cvt_bf16(rf[1][e]);
      h1[e] = cvt_bf16(rf[2][e]); h1[4 + e] = cvt_bf16(rf[3][e]);
    }
    b0v = __builtin_bit_cast(bf16x8, h0);
    b1v = __builtin_bit_cast(bf16x8, h1);
  };

  f32x16 acc1[8];
#pragma unroll
  for (int t = 0; t < 8; ++t)
#pragma unroll
    for (int k = 0; k < 16; ++k) acc1[t][k] = 0.0f;

  auto COMPUTE = [&](const unsigned char* bW, bf16x8 b0v, bf16x8 b1v) {
#pragma unroll
    for (int kc = 0; kc < 2; ++kc) {
      const bf16x8 bv = kc ? b1v : b0v;
#pragma unroll
      for (int nt = 0; nt < 8; ++nt) {
        bf16x8 av = __builtin_bit_cast(bf16x8,
            *(const us8*)(bW + (kc * 8 + nt) * 1024 + lane * 16));
        acc1[nt] = __builtin_amdgcn_mfma_f32_32x32x16_bf16(av, bv, acc1[nt], 0, 0, 0);
      }
    }
  };

  us8    rr[4][2];
  f32x4v rf[4][4];
  us8    xps[2][8];   // MODE 1: two slots; STRICT fold-before-reload

  auto XPLOAD = [&](int k, int slot) {
    us8* d = xps[slot];
#pragma unroll
    for (int tt = 0; tt < 2; ++tt) {
      const int t = 2 * k + tt;
      d[tt * 2 + 0]     = *(const us8*)(pXa + t * 16);
      d[tt * 2 + 1]     = *(const us8*)(pXa + t * 16 + 8);
      d[4 + tt * 2 + 0] = *(const us8*)(pXb + t * 16);
      d[4 + tt * 2 + 1] = *(const us8*)(pXb + t * 16 + 8);
    }
  };
  auto XPFOLD = [&](int k, int slot) {
    const us8* d = xps[slot];
#pragma unroll
    for (int tt = 0; tt < 2; ++tt) {
      const int t = 2 * k + tt;
#pragma unroll
      for (int j = 0; j < 16; ++j) {
        acc1[t][j] += cvt_f32(d[tt * 2 + (j >> 3)][j & 7]) +
                      cvt_f32(d[4 + tt * 2 + (j >> 3)][j & 7]);
      }
    }
  };

  if constexpr (MODE == 1) {
    // ---- specialized L1: all W1c+rows staged up front; XP folded in tail ---
    STG1(0); STG1(1); STG1(2); STG1(3);                 // 16 glls
    LROW(0, rr[0]); LROW(1, rr[1]); LROW(2, rr[2]); LROW(3, rr[3]);  // 8
    WAITV(4);                                            // rows0,1 + all W1 done
    asm volatile("s_waitcnt lgkmcnt(0)" ::: "memory");
    asm volatile("s_barrier" ::: "memory");
    {
      bf16x8 a0 = __builtin_bit_cast(bf16x8, rr[0][0]), a1 = __builtin_bit_cast(bf16x8, rr[0][1]);
      bf16x8 a2 = __builtin_bit_cast(bf16x8, rr[1][0]), a3 = __builtin_bit_cast(bf16x8, rr[1][1]);
      XPLOAD(0, 0); XPLOAD(1, 1);                        // +16
      __builtin_amdgcn_s_setprio(1);
      COMPUTE(lds, a0, a1);
      COMPUTE(lds + 16384, a2, a3);
      __builtin_amdgcn_s_setprio(0);
    }
    WAITV(16);                                           // rows2,3 ready (X0,X1 remain)
    {
      bf16x8 a0 = __builtin_bit_cast(bf16x8, rr[2][0]), a1 = __builtin_bit_cast(bf16x8, rr[2][1]);
      bf16x8 a2 = __builtin_bit_cast(bf16x8, rr[3][0]), a3 = __builtin_bit_cast(bf16x8, rr[3][1]);
      __builtin_amdgcn_s_setprio(1);
      COMPUTE(lds + 2 * 16384, a0, a1);
      COMPUTE(lds + 3 * 16384, a2, a3);
      __builtin_amdgcn_s_setprio(0);
    }
    asm volatile("s_waitcnt lgkmcnt(0)" ::: "memory");
    asm volatile("s_barrier" ::: "memory");              // all ds_reads done
    STG2(0); STG2(1);                                    // +8
    // outstanding now: X0(8), X1(8), STG2(8) = 24.
    // Strict fold-before-reload (R14 fix):
    WAITV(16);  XPFOLD(0, 0);                            // drain X0, fold slot0
    XPLOAD(2, 0);                                        // reload slot0 (+8)
    WAITV(16);  XPFOLD(1, 1);                            // drain X1, fold slot1
    XPLOAD(3, 1);                                        // reload slot1 (+8)
    WAITV(8);   XPFOLD(2, 0);                            // drain STG2+X2
    WAITV(0);   XPFOLD(3, 1);                            // drain X3
  } else {
    STG1(0); STG1(1);
    if constexpr (MODE == 0) { LROWF(0, rf[0]); LROWF(1, rf[1]); LROWF(2, rf[2]); LROWF(3, rf[3]); }
    else                     { LROW(0, rr[0]);  LROW(1, rr[1]);  LROW(2, rr[2]);  LROW(3, rr[3]); }

#pragma unroll
    for (int p = 0; p < NP; ++p) {
      const int s0 = 2 * p, s1 = 2 * p + 1;
      const int w = (p + 1 < NP) ? ((MODE == 0) ? 8 : 4) : 0;
      WAITV(w);
      asm volatile("s_waitcnt lgkmcnt(0)" ::: "memory");
      asm volatile("s_barrier" ::: "memory");

      bf16x8 a0v, a1v, c0v, c1v;
      if constexpr (MODE == 0) { MKBR(rf[s0 & 3], a0v, a1v); MKBR(rf[s1 & 3], c0v, c1v); }
      else {
        a0v = __builtin_bit_cast(bf16x8, rr[s0 & 3][0]); a1v = __builtin_bit_cast(bf16x8, rr[s0 & 3][1]);
        c0v = __builtin_bit_cast(bf16x8, rr[s1 & 3][0]); c1v = __builtin_bit_cast(bf16x8, rr[s1 & 3][1]);
      }
      if (p + 1 < NP) {
        STG1(s0 + 2); STG1(s1 + 2);
        if (p + 2 < NP) {
          if constexpr (MODE == 0) { LROWF(s0 + 4, rf[(s0 + 4) & 3]); LROWF(s1 + 4, rf[(s1 + 4) & 3]); }
          else                     { LROW(s0 + 4, rr[(s0 + 4) & 3]);  LROW(s1 + 4, rr[(s1 + 4) & 3]); }
        }
      }
      __builtin_amdgcn_s_setprio(1);
      COMPUTE(lds + (s0 & 3) * 16384, a0v, a1v);
      COMPUTE(lds + (s1 & 3) * 16384, c0v, c1v);
      __builtin_amdgcn_s_setprio(0);
    }
    STG2(0); STG2(1);
  }

  // ===== epilogue 1: bias+relu+cvt -> sigma-order A-frags (registers) =====
  u32x4 pa4[16];
#pragma unroll
  for (int t = 0; t < 8; ++t) {
#pragma unroll
    for (int q4 = 0; q4 < 4; ++q4) {
      const f32x4v bv4 = *(const f32x4v*)(b1 + t * 32 + q4 * 8 + g * 4);
      float v0 = fmaxf(acc1[t][q4 * 4 + 0] + bv4[0], 0.0f);
      float v1 = fmaxf(acc1[t][q4 * 4 + 1] + bv4[1], 0.0f);
      float v2 = fmaxf(acc1[t][q4 * 4 + 2] + bv4[2], 0.0f);
      float v3 = fmaxf(acc1[t][q4 * 4 + 3] + bv4[3], 0.0f);
      uint32_t lo, hi;
      asm("v_cvt_pk_bf16_f32 %0, %1, %2" : "=v"(lo) : "v"(v0), "v"(v1));
      asm("v_cvt_pk_bf16_f32 %0, %1, %2" : "=v"(hi) : "v"(v2), "v"(v3));
      pa4[t * 2 + (q4 >> 1)][(q4 & 1) * 2 + 0] = lo;
      pa4[t * 2 + (q4 >> 1)][(q4 & 1) * 2 + 1] = hi;
    }
  }

  // ================= layer 2: 2 chunk-pair phases =================
  f32x16 acc2[4];
#pragma unroll
  for (int nt = 0; nt < 4; ++nt)
#pragma unroll
    for (int k = 0; k < 16; ++k) acc2[nt][k] = 0.0f;

#pragma unroll
  for (int q = 0; q < 2; ++q) {
    WAITV(0);
    asm volatile("s_waitcnt lgkmcnt(0)" ::: "memory");
    asm volatile("s_barrier" ::: "memory");
    if (q == 0) { STG2(2); STG2(3); }
    __builtin_amdgcn_s_setprio(1);
#pragma unroll
    for (int ci = 0; ci < 2; ++ci) {
      const int c = q * 2 + ci;
      const unsigned char* bW = lds + ((c + NS1) & 3) * 16384;
#pragma unroll
      for (int kk = 0; kk < 4; ++kk) {
        const bf16x8 a2 = __builtin_bit_cast(bf16x8, pa4[c * 4 + kk]);
#pragma unroll
        for (int nt = 0; nt < 4; ++nt) {
          const bf16x8 bw = __builtin_bit_cast(bf16x8,
              *(const us8*)(bW + (kk * 4 + nt) * 1024 + lane * 16));
          acc2[nt] = __builtin_amdgcn_mfma_f32_32x32x16_bf16(a2, bw, acc2[nt], 0, 0, 0);
        }
      }
    }
    __builtin_amdgcn_s_setprio(0);
  }

  // ===== epilogue 2: bias+relu, bf16 stores (perm'd for MODE 0), pool =====
  float bias2[4];
#pragma unroll
  for (int nt = 0; nt < 4; ++nt) bias2[nt] = b2[nt * 32 + l31];

#pragma unroll
  for (int reg = 0; reg < 16; ++reg) {
    const int rowpat = (reg & 3) + ((reg >> 2) << 3) + g * 4;
    const int row = rowBlock + wid * 32 + rowpat;
    const bool ok = (row < nrows);
    size_t drow = 0;
    if (ok) drow = (size_t)((MODE == 0 && perm) ? perm[row] : row);
    float vs = 0.0f;
#pragma unroll
    for (int nt = 0; nt < 4; ++nt) {
      float v = fmaxf(acc2[nt][reg] + bias2[nt], 0.0f);
      vs += v;
      if (ok) dst[drow * 128 + nt * 32 + l31] = cvt_bf16(v);
    }
    if constexpr (POOL) {
#pragma unroll
      for (int m = 1; m <= 16; m <<= 1) vs += __shfl_xor(vs, m, 64);
      if (l31 == 0 && ok) pool_out[row] = vs;
    }
  }
}

// ---------------------------------------------------------------------------
// Workspace layout (bytes)
// ---------------------------------------------------------------------------
static constexpr size_t OFF_X    = 0;                          // N*128*2
static constexpr size_t OFF_E    = 5120000;                    // E*128*2 (sorted)
static constexpr size_t OFF_AGG  = 87040000;                   // N*128*2
static constexpr size_t OFF_PN1  = 92160000;
static constexpr size_t OFF_PN2  = OFF_PN1 + 65536;
static constexpr size_t OFF_PE1  = OFF_PN2 + 65536;
static constexpr size_t OFF_PE2  = OFF_PE1 + 65536;
static constexpr size_t OFF_PD1  = OFF_PE2 + 65536;            // 196608
static constexpr size_t OFF_PD2  = OFF_PD1 + 196608;
static constexpr size_t OFF_PM1  = OFF_PD2 + 65536;            // 131072
static constexpr size_t OFF_PM2  = OFF_PM1 + 131072;
static constexpr size_t OFF_CNT  = OFF_PM2 + 65536;            // N*4
static constexpr size_t OFF_OFFS = OFF_CNT + 80000;            // (N+1)*4
static constexpr size_t OFF_CUR  = OFF_OFFS + 80004;           // N*4
static constexpr size_t OFF_POS  = OFF_CUR + 80000;            // E*4
static constexpr size_t OFF_SSEND= OFF_POS + 1280000;          // E*4
static constexpr size_t OFF_SREC = OFF_SSEND + 1280000;        // E*4
static constexpr size_t OFF_XP   = ((OFF_SREC + 1280000 + 63) / 64) * 64;  // N*512*2

extern "C" void kernel_launch(void* const* d_in, const int* in_sizes, int n_in,
                              void* d_out, int out_size, void* d_ws, size_t ws_size,
                              hipStream_t stream) {
  const float* nodes = (const float*)d_in[0];
  const float* edges = (const float*)d_in[1];
  const int* senders = (const int*)d_in[2];
  const int* receivers = (const int*)d_in[3];
  const float* Wn1 = (const float*)d_in[4];  const float* bn1 = (const float*)d_in[5];
  const float* Wn2 = (const float*)d_in[6];  const float* bn2 = (const float*)d_in[7];
  const float* We1 = (const float*)d_in[8];  const float* be1 = (const float*)d_in[9];
  const float* We2 = (const float*)d_in[10]; const float* be2 = (const float*)d_in[11];
  const float* Wed1 = (const float*)d_in[12]; const float* bed1 = (const float*)d_in[13];
  const float* Wed2 = (const float*)d_in[14]; const float* bed2 = (const float*)d_in[15];
  const float* Wnd1 = (const float*)d_in[16]; const float* bnd1 = (const float*)d_in[17];
  const float* Wnd2 = (const float*)d_in[18]; const float* bnd2 = (const float*)d_in[19];

  char* ws = (char*)d_ws;
  unsigned short* xb   = (unsigned short*)(ws + OFF_X);
  unsigned short* eb   = (unsigned short*)(ws + OFF_E);
  unsigned short* aggb = (unsigned short*)(ws + OFF_AGG);
  unsigned short* Pn1  = (unsigned short*)(ws + OFF_PN1);
  unsigned short* Pn2  = (unsigned short*)(ws + OFF_PN2);
  unsigned short* Pe1  = (unsigned short*)(ws + OFF_PE1);
  unsigned short* Pe2  = (unsigned short*)(ws + OFF_PE2);
  unsigned short* Pd1  = (unsigned short*)(ws + OFF_PD1);
  unsigned short* Pd2  = (unsigned short*)(ws + OFF_PD2);
  unsigned short* Pm1  = (unsigned short*)(ws + OFF_PM1);
  unsigned short* Pm2  = (unsigned short*)(ws + OFF_PM2);
  int* cnt    = (int*)(ws + OFF_CNT);
  int* offs   = (int*)(ws + OFF_OFFS);
  int* cursor = (int*)(ws + OFF_CUR);
  int* pos    = (int*)(ws + OFF_POS);
  int* ssend  = (int*)(ws + OFF_SSEND);
  int* srecv  = (int*)(ws + OFF_SREC);
  unsigned short* XP = (unsigned short*)(ws + OFF_XP);
  float* outp = (float*)d_out;

  pack_w<<<128, 256, 0, stream>>>(Wn1, Pn1, 128, 256);
  pack_w2<<<128, 256, 0, stream>>>(Wn2, Pn2);
  pack_w<<<128, 256, 0, stream>>>(We1, Pe1, 128, 256);
  pack_w2<<<128, 256, 0, stream>>>(We2, Pe2);
  pack_w<<<384, 256, 0, stream>>>(Wed1, Pd1, 384, 256);
  pack_w2<<<128, 256, 0, stream>>>(Wed2, Pd2);
  pack_w<<<256, 256, 0, stream>>>(Wnd1, Pm1, 256, 256);
  pack_w2<<<128, 256, 0, stream>>>(Wnd2, Pm2);

  hipMemsetAsync(cnt, 0, (size_t)N_NODES * 4, stream);
  hist_k<<<1250, 256, 0, stream>>>(receivers, cnt, N_EDGES);
  scan_k<<<1, 1024, 0, stream>>>(cnt, offs, cursor, N_NODES);
  fill_k<<<1250, 256, 0, stream>>>(senders, receivers, cursor, pos, ssend, srecv, N_EDGES);

  const int nodeBlocks = (N_NODES + 127) / 128;  // 157
  const int edgeBlocks = N_EDGES / 128;          // 2500

  // embed stage (edge embeds scattered to receiver-sorted slots via pos)
  mlp_kernel<128, 0, 0><<<nodeBlocks, 256, 0, stream>>>(
      nodes, nullptr, nullptr, nullptr, nullptr, nullptr, nullptr,
      Pn1, bn1, Pn2, bn2, xb, nullptr, N_NODES);
  mlp_kernel<128, 0, 0><<<edgeBlocks, 256, 0, stream>>>(
      edges, nullptr, nullptr, nullptr, nullptr, nullptr, pos,
      Pe1, be1, Pe2, be2, eb, nullptr, N_EDGES);

  for (int it = 0; it < 2; ++it) {
    precompute_k<<<nodeBlocks, 256, 0, stream>>>(xb, Pd1, XP, N_NODES);
    mlp_kernel<128, 1, 0><<<edgeBlocks, 256, 0, stream>>>(
        nullptr, nullptr, eb, XP, ssend, srecv, nullptr,
        Pd1 + 8 * 8192, bed1, Pd2, bed2, eb, nullptr, N_EDGES);
    agg_k<<<(N_NODES + 3) / 4, 256, 0, stream>>>(eb, offs, aggb, N_NODES);
    mlp_kernel<256, 2, 1><<<nodeBlocks, 256, 0, stream>>>(
        nullptr, xb, nullptr, aggb, nullptr, nullptr, nullptr,
        Pm1, bnd1, Pm2, bnd2, xb, outp + (size_t)it * N_NODES, N_NODES);
  }
}

// Round 16
// 479.607 us; speedup vs baseline: 1.0522x; 1.0522x over previous
//
#include <hip/hip_runtime.h>
#include <stdint.h>

#define N_NODES 20000
#define N_EDGES 320000

typedef __attribute__((ext_vector_type(8)))  __bf16        bf16x8;
typedef __attribute__((ext_vector_type(16))) float         f32x16;
typedef __attribute__((ext_vector_type(4)))  float         f32x4v;
typedef __attribute__((ext_vector_type(4)))  uint32_t      u32x4;
typedef __attribute__((ext_vector_type(8)))  unsigned short us8;
typedef __attribute__((ext_vector_type(2)))  unsigned short us2;

static __device__ __forceinline__ unsigned short cvt_bf16(float f) {
  uint32_t u = __builtin_bit_cast(uint32_t, f);
  u = (u + 0x7fffu + ((u >> 16) & 1u)) >> 16;
  return (unsigned short)u;
}
static __device__ __forceinline__ float cvt_f32(unsigned short h) {
  uint32_t u = ((uint32_t)h) << 16;
  return __builtin_bit_cast(float, u);
}

// async global->LDS, 16B per lane; LDS dest = wave-uniform base (HW adds lane*16)
static __device__ __forceinline__ void gll16(const void* g, void* l) {
  __builtin_amdgcn_global_load_lds(
      (const __attribute__((address_space(1))) unsigned int*)g,
      (__attribute__((address_space(3))) unsigned int*)l, 16, 0, 0);
}

// literal-folded counted vmcnt wait (indices constant after full unroll)
#define WAITV(n) do { \
  if ((n) == 0)      asm volatile("s_waitcnt vmcnt(0)" ::: "memory"); \
  else if ((n) == 4) asm volatile("s_waitcnt vmcnt(4)" ::: "memory"); \
  else if ((n) == 8) asm volatile("s_waitcnt vmcnt(8)" ::: "memory"); \
  else               asm volatile("s_waitcnt vmcnt(12)" ::: "memory"); \
} while (0)

// ---------------------------------------------------------------------------
// Weight packing (verified R1-R15), fused into ONE launch.
// pack_w body: natural k-order; pack_w2 body: sigma k-order for the
// register-resident H handoff. Block-range dispatch, all sizes compile-time.
// ---------------------------------------------------------------------------
static __device__ __forceinline__ void pw_body(const float* __restrict__ W,
                                               unsigned short* __restrict__ out,
                                               int Ncols, int idx) {
  int e    = idx & 7;
  int lane = (idx >> 3) & 63;
  int t    = idx >> 9;
  int ntiles = Ncols >> 5;
  int nt = t % ntiles;
  int ks = t / ntiles;
  int k = ks * 16 + (lane >> 5) * 8 + e;
  int c = nt * 32 + (lane & 31);
  out[idx] = cvt_bf16(W[(size_t)k * Ncols + c]);
}
static __device__ __forceinline__ void pw2_body(const float* __restrict__ W,
                                                unsigned short* __restrict__ out,
                                                int idx) {
  int e    = idx & 7;
  int lane = (idx >> 3) & 63;
  int t    = idx >> 9;
  int nt = t & 3, ks = t >> 2;
  int k = ks * 16 + ((lane >> 5) << 2) + (e & 3) + ((e >> 2) << 3);
  int c = nt * 32 + (lane & 31);
  out[idx] = cvt_bf16(W[(size_t)k * 128 + c]);
}

__global__ void pack_all(const float* __restrict__ Wn1, const float* __restrict__ Wn2,
                         const float* __restrict__ We1, const float* __restrict__ We2,
                         const float* __restrict__ Wed1, const float* __restrict__ Wed2,
                         const float* __restrict__ Wnd1, const float* __restrict__ Wnd2,
                         unsigned short* __restrict__ Pn1, unsigned short* __restrict__ Pn2,
                         unsigned short* __restrict__ Pe1, unsigned short* __restrict__ Pe2,
                         unsigned short* __restrict__ Pd1, unsigned short* __restrict__ Pd2,
                         unsigned short* __restrict__ Pm1, unsigned short* __restrict__ Pm2) {
  const int b = blockIdx.x, tid = threadIdx.x;
  // blocks: [0,128) Wn1 | [128,256) We1 | [256,640) Wed1 | [640,896) Wnd1
  //         [896,1024) Wn2 | [1024,1152) We2 | [1152,1280) Wed2 | [1280,1408) Wnd2
  if      (b <  128) pw_body(Wn1,  Pn1, 256, (b        ) * 256 + tid);
  else if (b <  256) pw_body(We1,  Pe1, 256, (b -  128) * 256 + tid);
  else if (b <  640) pw_body(Wed1, Pd1, 256, (b -  256) * 256 + tid);
  else if (b <  896) pw_body(Wnd1, Pm1, 256, (b -  640) * 256 + tid);
  else if (b < 1024) pw2_body(Wn2,  Pn2, (b -  896) * 256 + tid);
  else if (b < 1152) pw2_body(We2,  Pe2, (b - 1024) * 256 + tid);
  else if (b < 1280) pw2_body(Wed2, Pd2, (b - 1152) * 256 + tid);
  else               pw2_body(Wnd2, Pm2, (b - 1280) * 256 + tid);
}

// ---------------------------------------------------------------------------
// CSR build; fill_k emits pos (edge->sorted slot) + sorted senders/receivers.
// ---------------------------------------------------------------------------
__global__ void hist_k(const int* __restrict__ recv, int* __restrict__ cnt, int n) {
  int i = blockIdx.x * 256 + threadIdx.x;
  if (i < n) atomicAdd(&cnt[recv[i]], 1);
}

__global__ void scan_k(const int* __restrict__ cnt, int* __restrict__ off,
                       int* __restrict__ cursor, int n) {
  __shared__ int part[1024];
  int t = threadIdx.x;
  int chunk = (n + 1023) / 1024;
  int base = t * chunk;
  int s = 0;
  for (int i = 0; i < chunk; ++i) { int idx = base + i; if (idx < n) s += cnt[idx]; }
  part[t] = s;
  __syncthreads();
  for (int d = 1; d < 1024; d <<= 1) {
    int v = (t >= d) ? part[t - d] : 0;
    __syncthreads();
    part[t] += v;
    __syncthreads();
  }
  int prefix = (t > 0) ? part[t - 1] : 0;
  for (int i = 0; i < chunk; ++i) {
    int idx = base + i;
    if (idx < n) { off[idx] = prefix; cursor[idx] = prefix; prefix += cnt[idx]; }
  }
  if (t == 1023) off[n] = part[1023];
}

__global__ void fill_k(const int* __restrict__ send, const int* __restrict__ recv,
                       int* __restrict__ cursor, int* __restrict__ pos,
                       int* __restrict__ ssend, int* __restrict__ srecv, int n) {
  int i = blockIdx.x * 256 + threadIdx.x;
  if (i < n) {
    int p = atomicAdd(&cursor[recv[i]], 1);
    pos[i] = p;
    ssend[p] = send[i];
    srecv[p] = recv[i];
  }
}

// agg[n][:] = sum of CONTIGUOUS sorted e rows [off[n], off[n+1]) — streaming.
__global__ void agg_k(const unsigned short* __restrict__ eb, const int* __restrict__ off,
                      unsigned short* __restrict__ aggb, int n) {
  int node = blockIdx.x * 4 + (threadIdx.x >> 6);
  if (node >= n) return;
  int lane = threadIdx.x & 63;
  float a0 = 0.f, a1 = 0.f;
  int s = off[node], t = off[node + 1];
  for (int q = s; q < t; ++q) {
    us2 v = *(const us2*)(eb + (size_t)q * 128 + lane * 2);
    a0 += cvt_f32(v[0]);
    a1 += cvt_f32(v[1]);
  }
  us2 r; r[0] = cvt_bf16(a0); r[1] = cvt_bf16(a1);
  *(us2*)(aggb + (size_t)node * 128 + lane * 2) = r;
}

// ---------------------------------------------------------------------------
// Fused 2-layer MLP (verified structure R6-R15): out = relu(relu(A@W1+b1)@W2+b2)
// 128 rows/block, 4 waves; wave-tile = FULL 256 hidden x 32 rows.
// L1 flipped; H handoff IN REGISTERS (sigma order). Pipeline = R11/R13:
// two K-steps/phase, 4x16KB rotation, one barrier/phase, 2-phase-ahead row
// prefetch (consume-before-clobber), NS1-shifted W2 buffer reuse.
//  MODE 0: A = srcf f32 (KIN=128); optional perm scatter-write (embed-edge).
//  MODE 1: edge-model in RECEIVER-SORTED order (KIN=384): e read/write
//          contiguous; x gathered via ssend/srecv (passed as senders/receivers).
//  MODE 2: A = [x, agg] bf16 (KIN=256) + fused pool.
// ---------------------------------------------------------------------------
template <int KIN, int MODE, int POOL>
__global__ __launch_bounds__(256, 2)
void mlp_kernel(const float* __restrict__ srcf,
                const unsigned short* __restrict__ xb,
                const unsigned short* __restrict__ ebuf,
                const unsigned short* __restrict__ aggb,
                const int* __restrict__ senders,
                const int* __restrict__ receivers,
                const int* __restrict__ perm,
                const unsigned short* __restrict__ P1,
                const float* __restrict__ b1,
                const unsigned short* __restrict__ P2,
                const float* __restrict__ b2,
                unsigned short* __restrict__ dst,
                float* __restrict__ pool_out,
                int nrows) {
  constexpr int NS1 = KIN / 32;                 // 4 / 12 / 8 (even)
  constexpr int NP  = NS1 / 2;                  // phases
  __shared__ __align__(16) unsigned char lds[65536];   // 4 x 16KB rotation

  const int tid  = threadIdx.x;
  const int lane = tid & 63;
  const int wid  = tid >> 6;
  const int g    = lane >> 5;
  const int l31  = lane & 31;
  const int rowBlock = blockIdx.x << 7;

  const unsigned char* P1b = (const unsigned char*)P1;
  const unsigned char* P2b = (const unsigned char*)P2;

  int grow = rowBlock + wid * 32 + l31;
  if (grow >= nrows) grow = nrows - 1;

  const unsigned short *pS = nullptr, *pR = nullptr, *pE = nullptr;
  const unsigned short *pX = nullptr, *pAg = nullptr;
  const float* fb = nullptr;
  if constexpr (MODE == 0) {
    fb = srcf + (size_t)grow * KIN;
  } else if constexpr (MODE == 1) {
    pS = xb + (size_t)senders[grow] * 128;     // ssend[grow] (sorted order)
    pR = xb + (size_t)receivers[grow] * 128;   // srecv[grow] (non-decreasing)
    pE = ebuf + (size_t)grow * 128;            // contiguous sorted e
  } else {
    pX  = xb + (size_t)grow * 128;
    pAg = aggb + (size_t)grow * 128;
  }

  auto STG1 = [&](int s) {
    unsigned char* bW = lds + (s & 3) * 16384;
#pragma unroll
    for (int c = 0; c < 4; ++c)
      gll16(P1b + (size_t)s * 16384 + c * 4096 + tid * 16,
            bW + c * 4096 + wid * 1024);
  };
  auto STG2 = [&](int c) {
    unsigned char* bW = lds + ((c + NS1) & 3) * 16384;
#pragma unroll
    for (int q = 0; q < 4; ++q)
      gll16(P2b + (size_t)c * 16384 + q * 4096 + tid * 16,
            bW + q * 4096 + wid * 1024);
  };

  auto LROW = [&](int s, us8* o) {
    const int k0s = s * 32;
    const unsigned short* p;
    if constexpr (MODE == 1) {
      const int seg = k0s >> 7;
      p = (seg == 0) ? pS : (seg == 1) ? pR : pE;
    } else {
      p = (k0s >> 7) ? pAg : pX;
    }
    const int ko = k0s & 127;
    o[0] = *(const us8*)(p + ko + g * 8);
    o[1] = *(const us8*)(p + ko + 16 + g * 8);
  };
  auto LROWF = [&](int s, f32x4v* rf) {
    const float* p = fb + s * 32 + g * 8;
    rf[0] = *(const f32x4v*)(p);
    rf[1] = *(const f32x4v*)(p + 4);
    rf[2] = *(const f32x4v*)(p + 16);
    rf[3] = *(const f32x4v*)(p + 20);
  };
  auto MKBR = [&](const f32x4v* rf, bf16x8& b0v, bf16x8& b1v) {
    us8 h0, h1;
#pragma unroll
    for (int e = 0; e < 4; ++e) {
      h0[e] = cvt_bf16(rf[0][e]); h0[4 + e] = cvt_bf16(rf[1][e]);
      h1[e] = cvt_bf16(rf[2][e]); h1[4 + e] = cvt_bf16(rf[3][e]);
    }
    b0v = __builtin_bit_cast(bf16x8, h0);
    b1v = __builtin_bit_cast(bf16x8, h1);
  };

  // ================= layer 1 =================
  f32x16 acc1[8];
#pragma unroll
  for (int t = 0; t < 8; ++t)
#pragma unroll
    for (int k = 0; k < 16; ++k) acc1[t][k] = 0.0f;

  auto COMPUTE = [&](const unsigned char* bW, bf16x8 b0v, bf16x8 b1v) {
#pragma unroll
    for (int kc = 0; kc < 2; ++kc) {
      const bf16x8 bv = kc ? b1v : b0v;
#pragma unroll
      for (int nt = 0; nt < 8; ++nt) {
        bf16x8 av = __builtin_bit_cast(bf16x8,
            *(const us8*)(bW + (kc * 8 + nt) * 1024 + lane * 16));
        acc1[nt] = __builtin_amdgcn_mfma_f32_32x32x16_bf16(av, bv, acc1[nt], 0, 0, 0);
      }
    }
  };

  us8    rr[4][2];   // 4-slot row rotation (compile-time indexed)
  f32x4v rf[4][4];   // MODE 0

  STG1(0); STG1(1);
  if constexpr (MODE == 0) { LROWF(0, rf[0]); LROWF(1, rf[1]); LROWF(2, rf[2]); LROWF(3, rf[3]); }
  else                     { LROW(0, rr[0]);  LROW(1, rr[1]);  LROW(2, rr[2]);  LROW(3, rr[3]); }

#pragma unroll
  for (int p = 0; p < NP; ++p) {
    const int s0 = 2 * p, s1 = 2 * p + 1;
    const int w = (p + 1 < NP) ? ((MODE == 0) ? 8 : 4) : 0;
    WAITV(w);
    asm volatile("s_waitcnt lgkmcnt(0)" ::: "memory");
    asm volatile("s_barrier" ::: "memory");

    // consume rows into locals FIRST (R10 WAR fix), then issue next-phase VMEM
    bf16x8 a0v, a1v, c0v, c1v;
    if constexpr (MODE == 0) { MKBR(rf[s0 & 3], a0v, a1v); MKBR(rf[s1 & 3], c0v, c1v); }
    else {
      a0v = __builtin_bit_cast(bf16x8, rr[s0 & 3][0]); a1v = __builtin_bit_cast(bf16x8, rr[s0 & 3][1]);
      c0v = __builtin_bit_cast(bf16x8, rr[s1 & 3][0]); c1v = __builtin_bit_cast(bf16x8, rr[s1 & 3][1]);
    }

    if (p + 1 < NP) {
      STG1(s0 + 2); STG1(s1 + 2);
      if (p + 2 < NP) {
        if constexpr (MODE == 0) { LROWF(s0 + 4, rf[(s0 + 4) & 3]); LROWF(s1 + 4, rf[(s1 + 4) & 3]); }
        else                     { LROW(s0 + 4, rr[(s0 + 4) & 3]);  LROW(s1 + 4, rr[(s1 + 4) & 3]); }
      }
    }

    __builtin_amdgcn_s_setprio(1);
    COMPUTE(lds + (s0 & 3) * 16384, a0v, a1v);
    COMPUTE(lds + (s1 & 3) * 16384, c0v, c1v);
    __builtin_amdgcn_s_setprio(0);
  }

  // W2 chunks 0,1 -> bufs (NS1)&3,(NS1+1)&3: distinct from the two bufs the
  // final L1 phase read -> safe without a barrier.
  STG2(0);
  STG2(1);

  // ===== epilogue 1: bias+relu+cvt -> sigma-order A-frags (registers) =====
  u32x4 pa4[16];
#pragma unroll
  for (int t = 0; t < 8; ++t) {
#pragma unroll
    for (int q4 = 0; q4 < 4; ++q4) {
      const f32x4v bv4 = *(const f32x4v*)(b1 + t * 32 + q4 * 8 + g * 4);
      float v0 = fmaxf(acc1[t][q4 * 4 + 0] + bv4[0], 0.0f);
      float v1 = fmaxf(acc1[t][q4 * 4 + 1] + bv4[1], 0.0f);
      float v2 = fmaxf(acc1[t][q4 * 4 + 2] + bv4[2], 0.0f);
      float v3 = fmaxf(acc1[t][q4 * 4 + 3] + bv4[3], 0.0f);
      uint32_t lo, hi;
      asm("v_cvt_pk_bf16_f32 %0, %1, %2" : "=v"(lo) : "v"(v0), "v"(v1));
      asm("v_cvt_pk_bf16_f32 %0, %1, %2" : "=v"(hi) : "v"(v2), "v"(v3));
      pa4[t * 2 + (q4 >> 1)][(q4 & 1) * 2 + 0] = lo;
      pa4[t * 2 + (q4 >> 1)][(q4 & 1) * 2 + 1] = hi;
    }
  }

  // ================= layer 2: 2 chunk-pair phases =================
  f32x16 acc2[4];
#pragma unroll
  for (int nt = 0; nt < 4; ++nt)
#pragma unroll
    for (int k = 0; k < 16; ++k) acc2[nt][k] = 0.0f;

#pragma unroll
  for (int q = 0; q < 2; ++q) {
    WAITV(0);
    asm volatile("s_waitcnt lgkmcnt(0)" ::: "memory");
    asm volatile("s_barrier" ::: "memory");
    if (q == 0) { STG2(2); STG2(3); }   // bufs freed by the q0 barrier
    __builtin_amdgcn_s_setprio(1);
#pragma unroll
    for (int ci = 0; ci < 2; ++ci) {
      const int c = q * 2 + ci;
      const unsigned char* bW = lds + ((c + NS1) & 3) * 16384;
#pragma unroll
      for (int kk = 0; kk < 4; ++kk) {
        const bf16x8 a2 = __builtin_bit_cast(bf16x8, pa4[c * 4 + kk]);
#pragma unroll
        for (int nt = 0; nt < 4; ++nt) {
          const bf16x8 bw = __builtin_bit_cast(bf16x8,
              *(const us8*)(bW + (kk * 4 + nt) * 1024 + lane * 16));
          acc2[nt] = __builtin_amdgcn_mfma_f32_32x32x16_bf16(a2, bw, acc2[nt], 0, 0, 0);
        }
      }
    }
    __builtin_amdgcn_s_setprio(0);
  }

  // ===== epilogue 2: bias+relu, bf16 stores (perm scatter for MODE 0), pool =====
  float bias2[4];
#pragma unroll
  for (int nt = 0; nt < 4; ++nt) bias2[nt] = b2[nt * 32 + l31];

#pragma unroll
  for (int reg = 0; reg < 16; ++reg) {
    const int rowpat = (reg & 3) + ((reg >> 2) << 3) + g * 4;
    const int row = rowBlock + wid * 32 + rowpat;
    const bool ok = (row < nrows);
    size_t drow = 0;
    if (ok) drow = (size_t)((MODE == 0 && perm) ? perm[row] : row);
    float vs = 0.0f;
#pragma unroll
    for (int nt = 0; nt < 4; ++nt) {
      float v = fmaxf(acc2[nt][reg] + bias2[nt], 0.0f);
      vs += v;
      if (ok) dst[drow * 128 + nt * 32 + l31] = cvt_bf16(v);
    }
    if constexpr (POOL) {
#pragma unroll
      for (int m = 1; m <= 16; m <<= 1) vs += __shfl_xor(vs, m, 64);
      if (l31 == 0 && ok) pool_out[row] = vs;
    }
  }
}

// ---------------------------------------------------------------------------
// Workspace layout (bytes)
// ---------------------------------------------------------------------------
static constexpr size_t OFF_X    = 0;                          // N*128*2
static constexpr size_t OFF_E    = 5120000;                    // E*128*2 (sorted)
static constexpr size_t OFF_AGG  = 87040000;                   // N*128*2
static constexpr size_t OFF_PN1  = 92160000;
static constexpr size_t OFF_PN2  = OFF_PN1 + 65536;
static constexpr size_t OFF_PE1  = OFF_PN2 + 65536;
static constexpr size_t OFF_PE2  = OFF_PE1 + 65536;
static constexpr size_t OFF_PD1  = OFF_PE2 + 65536;            // 196608
static constexpr size_t OFF_PD2  = OFF_PD1 + 196608;
static constexpr size_t OFF_PM1  = OFF_PD2 + 65536;            // 131072
static constexpr size_t OFF_PM2  = OFF_PM1 + 131072;
static constexpr size_t OFF_CNT  = OFF_PM2 + 65536;            // N*4
static constexpr size_t OFF_OFFS = OFF_CNT + 80000;            // (N+1)*4
static constexpr size_t OFF_CUR  = OFF_OFFS + 80004;           // N*4
static constexpr size_t OFF_POS  = OFF_CUR + 80000;            // E*4
static constexpr size_t OFF_SSEND= OFF_POS + 1280000;          // E*4
static constexpr size_t OFF_SREC = OFF_SSEND + 1280000;        // E*4

extern "C" void kernel_launch(void* const* d_in, const int* in_sizes, int n_in,
                              void* d_out, int out_size, void* d_ws, size_t ws_size,
                              hipStream_t stream) {
  const float* nodes = (const float*)d_in[0];
  const float* edges = (const float*)d_in[1];
  const int* senders = (const int*)d_in[2];
  const int* receivers = (const int*)d_in[3];
  const float* Wn1 = (const float*)d_in[4];  const float* bn1 = (const float*)d_in[5];
  const float* Wn2 = (const float*)d_in[6];  const float* bn2 = (const float*)d_in[7];
  const float* We1 = (const float*)d_in[8];  const float* be1 = (const float*)d_in[9];
  const float* We2 = (const float*)d_in[10]; const float* be2 = (const float*)d_in[11];
  const float* Wed1 = (const float*)d_in[12]; const float* bed1 = (const float*)d_in[13];
  const float* Wed2 = (const float*)d_in[14]; const float* bed2 = (const float*)d_in[15];
  const float* Wnd1 = (const float*)d_in[16]; const float* bnd1 = (const float*)d_in[17];
  const float* Wnd2 = (const float*)d_in[18]; const float* bnd2 = (const float*)d_in[19];

  char* ws = (char*)d_ws;
  unsigned short* xb   = (unsigned short*)(ws + OFF_X);
  unsigned short* eb   = (unsigned short*)(ws + OFF_E);
  unsigned short* aggb = (unsigned short*)(ws + OFF_AGG);
  unsigned short* Pn1  = (unsigned short*)(ws + OFF_PN1);
  unsigned short* Pn2  = (unsigned short*)(ws + OFF_PN2);
  unsigned short* Pe1  = (unsigned short*)(ws + OFF_PE1);
  unsigned short* Pe2  = (unsigned short*)(ws + OFF_PE2);
  unsigned short* Pd1  = (unsigned short*)(ws + OFF_PD1);
  unsigned short* Pd2  = (unsigned short*)(ws + OFF_PD2);
  unsigned short* Pm1  = (unsigned short*)(ws + OFF_PM1);
  unsigned short* Pm2  = (unsigned short*)(ws + OFF_PM2);
  int* cnt    = (int*)(ws + OFF_CNT);
  int* offs   = (int*)(ws + OFF_OFFS);
  int* cursor = (int*)(ws + OFF_CUR);
  int* pos    = (int*)(ws + OFF_POS);
  int* ssend  = (int*)(ws + OFF_SSEND);
  int* srecv  = (int*)(ws + OFF_SREC);
  float* outp = (float*)d_out;

  // all 8 weight packs in ONE launch
  pack_all<<<1408, 256, 0, stream>>>(Wn1, Wn2, We1, We2, Wed1, Wed2, Wnd1, Wnd2,
                                     Pn1, Pn2, Pe1, Pe2, Pd1, Pd2, Pm1, Pm2);

  // CSR for segment_sum over receivers; pos + sorted index arrays
  hipMemsetAsync(cnt, 0, (size_t)N_NODES * 4, stream);
  hist_k<<<1250, 256, 0, stream>>>(receivers, cnt, N_EDGES);
  scan_k<<<1, 1024, 0, stream>>>(cnt, offs, cursor, N_NODES);
  fill_k<<<1250, 256, 0, stream>>>(senders, receivers, cursor, pos, ssend, srecv, N_EDGES);

  const int nodeBlocks = (N_NODES + 127) / 128;  // 157
  const int edgeBlocks = N_EDGES / 128;          // 2500

  // embed stage (edge embeds scattered to receiver-sorted slots via pos)
  mlp_kernel<128, 0, 0><<<nodeBlocks, 256, 0, stream>>>(
      nodes, nullptr, nullptr, nullptr, nullptr, nullptr, nullptr,
      Pn1, bn1, Pn2, bn2, xb, nullptr, N_NODES);
  mlp_kernel<128, 0, 0><<<edgeBlocks, 256, 0, stream>>>(
      edges, nullptr, nullptr, nullptr, nullptr, nullptr, pos,
      Pe1, be1, Pe2, be2, eb, nullptr, N_EDGES);

  for (int it = 0; it < 2; ++it) {
    // edge-model in receiver-sorted order: e contiguous in+out, x gathered
    mlp_kernel<384, 1, 0><<<edgeBlocks, 256, 0, stream>>>(
        nullptr, xb, eb, nullptr, ssend, srecv, nullptr,
        Pd1, bed1, Pd2, bed2, eb, nullptr, N_EDGES);
    agg_k<<<(N_NODES + 3) / 4, 256, 0, stream>>>(eb, offs, aggb, N_NODES);
    mlp_kernel<256, 2, 1><<<nodeBlocks, 256, 0, stream>>>(
        nullptr, xb, nullptr, aggb, nullptr, nullptr, nullptr,
        Pm1, bnd1, Pm2, bnd2, xb, outp + (size_t)it * N_NODES, N_NODES);
  }
}

// Round 17
// 476.918 us; speedup vs baseline: 1.0582x; 1.0056x over previous
//
#include <hip/hip_runtime.h>
#include <stdint.h>

#define N_NODES 20000
#define N_EDGES 320000
#define NODE_BLOCKS 157   // (N_NODES+127)/128
#define EDGE_BLOCKS 2500  // N_EDGES/128

typedef __attribute__((ext_vector_type(8)))  __bf16        bf16x8;
typedef __attribute__((ext_vector_type(16))) float         f32x16;
typedef __attribute__((ext_vector_type(4)))  float         f32x4v;
typedef __attribute__((ext_vector_type(4)))  uint32_t      u32x4;
typedef __attribute__((ext_vector_type(8)))  unsigned short us8;
typedef __attribute__((ext_vector_type(2)))  unsigned short us2;

static __device__ __forceinline__ unsigned short cvt_bf16(float f) {
  uint32_t u = __builtin_bit_cast(uint32_t, f);
  u = (u + 0x7fffu + ((u >> 16) & 1u)) >> 16;
  return (unsigned short)u;
}
static __device__ __forceinline__ float cvt_f32(unsigned short h) {
  uint32_t u = ((uint32_t)h) << 16;
  return __builtin_bit_cast(float, u);
}

// async global->LDS, 16B per lane; LDS dest = wave-uniform base (HW adds lane*16)
static __device__ __forceinline__ void gll16(const void* g, void* l) {
  __builtin_amdgcn_global_load_lds(
      (const __attribute__((address_space(1))) unsigned int*)g,
      (__attribute__((address_space(3))) unsigned int*)l, 16, 0, 0);
}

// literal-folded counted vmcnt wait (indices constant after full unroll)
#define WAITV(n) do { \
  if ((n) == 0)      asm volatile("s_waitcnt vmcnt(0)" ::: "memory"); \
  else if ((n) == 4) asm volatile("s_waitcnt vmcnt(4)" ::: "memory"); \
  else if ((n) == 8) asm volatile("s_waitcnt vmcnt(8)" ::: "memory"); \
  else               asm volatile("s_waitcnt vmcnt(12)" ::: "memory"); \
} while (0)

// ---------------------------------------------------------------------------
// Weight packing (verified R1-R16) + hist, fused into ONE launch.
// ---------------------------------------------------------------------------
static __device__ __forceinline__ void pw_body(const float* __restrict__ W,
                                               unsigned short* __restrict__ out,
                                               int Ncols, int idx) {
  int e    = idx & 7;
  int lane = (idx >> 3) & 63;
  int t    = idx >> 9;
  int ntiles = Ncols >> 5;
  int nt = t % ntiles;
  int ks = t / ntiles;
  int k = ks * 16 + (lane >> 5) * 8 + e;
  int c = nt * 32 + (lane & 31);
  out[idx] = cvt_bf16(W[(size_t)k * Ncols + c]);
}
static __device__ __forceinline__ void pw2_body(const float* __restrict__ W,
                                                unsigned short* __restrict__ out,
                                                int idx) {
  int e    = idx & 7;
  int lane = (idx >> 3) & 63;
  int t    = idx >> 9;
  int nt = t & 3, ks = t >> 2;
  int k = ks * 16 + ((lane >> 5) << 2) + (e & 3) + ((e >> 2) << 3);
  int c = nt * 32 + (lane & 31);
  out[idx] = cvt_bf16(W[(size_t)k * 128 + c]);
}

__global__ void pack_all(const float* __restrict__ Wn1, const float* __restrict__ Wn2,
                         const float* __restrict__ We1, const float* __restrict__ We2,
                         const float* __restrict__ Wed1, const float* __restrict__ Wed2,
                         const float* __restrict__ Wnd1, const float* __restrict__ Wnd2,
                         unsigned short* __restrict__ Pn1, unsigned short* __restrict__ Pn2,
                         unsigned short* __restrict__ Pe1, unsigned short* __restrict__ Pe2,
                         unsigned short* __restrict__ Pd1, unsigned short* __restrict__ Pd2,
                         unsigned short* __restrict__ Pm1, unsigned short* __restrict__ Pm2,
                         const int* __restrict__ recv, int* __restrict__ cnt) {
  const int b = blockIdx.x, tid = threadIdx.x;
  // [0,128) Wn1 | [128,256) We1 | [256,640) Wed1 | [640,896) Wnd1
  // [896,1024) Wn2 | [1024,1152) We2 | [1152,1280) Wed2 | [1280,1408) Wnd2
  // [1408,2658) hist over receivers
  if      (b <  128) pw_body(Wn1,  Pn1, 256, (b        ) * 256 + tid);
  else if (b <  256) pw_body(We1,  Pe1, 256, (b -  128) * 256 + tid);
  else if (b <  640) pw_body(Wed1, Pd1, 256, (b -  256) * 256 + tid);
  else if (b <  896) pw_body(Wnd1, Pm1, 256, (b -  640) * 256 + tid);
  else if (b < 1024) pw2_body(Wn2,  Pn2, (b -  896) * 256 + tid);
  else if (b < 1152) pw2_body(We2,  Pe2, (b - 1024) * 256 + tid);
  else if (b < 1280) pw2_body(Wed2, Pd2, (b - 1152) * 256 + tid);
  else if (b < 1408) pw2_body(Wnd2, Pm2, (b - 1280) * 256 + tid);
  else {
    int i = (b - 1408) * 256 + tid;
    if (i < N_EDGES) atomicAdd(&cnt[recv[i]], 1);
  }
}

// ---------------------------------------------------------------------------
// CSR build; fill_k emits pos (edge->sorted slot) + sorted senders/receivers.
// ---------------------------------------------------------------------------
__global__ void scan_k(const int* __restrict__ cnt, int* __restrict__ off,
                       int* __restrict__ cursor, int n) {
  __shared__ int part[1024];
  int t = threadIdx.x;
  int chunk = (n + 1023) / 1024;
  int base = t * chunk;
  int s = 0;
  for (int i = 0; i < chunk; ++i) { int idx = base + i; if (idx < n) s += cnt[idx]; }
  part[t] = s;
  __syncthreads();
  for (int d = 1; d < 1024; d <<= 1) {
    int v = (t >= d) ? part[t - d] : 0;
    __syncthreads();
    part[t] += v;
    __syncthreads();
  }
  int prefix = (t > 0) ? part[t - 1] : 0;
  for (int i = 0; i < chunk; ++i) {
    int idx = base + i;
    if (idx < n) { off[idx] = prefix; cursor[idx] = prefix; prefix += cnt[idx]; }
  }
  if (t == 1023) off[n] = part[1023];
}

__global__ void fill_k(const int* __restrict__ send, const int* __restrict__ recv,
                       int* __restrict__ cursor, int* __restrict__ pos,
                       int* __restrict__ ssend, int* __restrict__ srecv, int n) {
  int i = blockIdx.x * 256 + threadIdx.x;
  if (i < n) {
    int p = atomicAdd(&cursor[recv[i]], 1);
    pos[i] = p;
    ssend[p] = send[i];
    srecv[p] = recv[i];
  }
}

// agg[n][:] = sum of CONTIGUOUS sorted e rows [off[n], off[n+1]) — streaming.
__global__ void agg_k(const unsigned short* __restrict__ eb, const int* __restrict__ off,
                      unsigned short* __restrict__ aggb, int n) {
  int node = blockIdx.x * 4 + (threadIdx.x >> 6);
  if (node >= n) return;
  int lane = threadIdx.x & 63;
  float a0 = 0.f, a1 = 0.f;
  int s = off[node], t = off[node + 1];
  for (int q = s; q < t; ++q) {
    us2 v = *(const us2*)(eb + (size_t)q * 128 + lane * 2);
    a0 += cvt_f32(v[0]);
    a1 += cvt_f32(v[1]);
  }
  us2 r; r[0] = cvt_bf16(a0); r[1] = cvt_bf16(a1);
  *(us2*)(aggb + (size_t)node * 128 + lane * 2) = r;
}

// ---------------------------------------------------------------------------
// Fused 2-layer MLP (verified structure R6-R16): out = relu(relu(A@W1+b1)@W2+b2)
// 128 rows/block, 4 waves; wave-tile = FULL 256 hidden x 32 rows.
// L1 flipped; H handoff IN REGISTERS (sigma order). Pipeline = R11/R13/R16.
//  MODE 0: A = srcf f32 (KIN=128); optional perm scatter-write.
//  MODE 1: edge-model in RECEIVER-SORTED order (KIN=384).
//  MODE 2: A = [x, agg] bf16 (KIN=256) + fused pool.
//  MODE 3: DUAL EMBED (KIN=128): blocks [0,NODE_BLOCKS) = node set
//          (srcf->dst), rest = edge set (srcf2->dst2 via perm scatter).
//          Wave-uniform select; MODE-0 body otherwise unchanged.
// ---------------------------------------------------------------------------
template <int KIN, int MODE, int POOL>
__global__ __launch_bounds__(256, 2)
void mlp_kernel(const float* __restrict__ srcf,
                const unsigned short* __restrict__ xb,
                const unsigned short* __restrict__ ebuf,
                const unsigned short* __restrict__ aggb,
                const int* __restrict__ senders,
                const int* __restrict__ receivers,
                const int* __restrict__ perm,
                const unsigned short* __restrict__ P1,
                const float* __restrict__ b1,
                const unsigned short* __restrict__ P2,
                const float* __restrict__ b2,
                unsigned short* __restrict__ dst,
                float* __restrict__ pool_out,
                int nrows,
                const float* __restrict__ srcf2 = nullptr,
                const unsigned short* __restrict__ P1B = nullptr,
                const float* __restrict__ b1B = nullptr,
                const unsigned short* __restrict__ P2B = nullptr,
                const float* __restrict__ b2B = nullptr,
                unsigned short* __restrict__ dst2 = nullptr) {
  constexpr int NS1 = KIN / 32;                 // 4 / 12 / 8 (even)
  constexpr int NP  = NS1 / 2;                  // phases
  __shared__ __align__(16) unsigned char lds[65536];   // 4 x 16KB rotation

  const int tid  = threadIdx.x;
  const int lane = tid & 63;
  const int wid  = tid >> 6;
  const int g    = lane >> 5;
  const int l31  = lane & 31;

  // MODE 3: wave-uniform set selection
  bool isNode = false;
  int rowBlock, nr = nrows;
  const float* fsrc = srcf;
  const int* permsel = perm;
  unsigned short* dsel = dst;
  if constexpr (MODE == 3) {
    isNode = (blockIdx.x < NODE_BLOCKS);
    if (isNode) {
      rowBlock = blockIdx.x << 7;          nr = N_NODES;
      fsrc = srcf;   permsel = nullptr;    dsel = dst;
    } else {
      rowBlock = (blockIdx.x - NODE_BLOCKS) << 7;  nr = N_EDGES;
      fsrc = srcf2;  permsel = perm;       dsel = dst2;
    }
  } else {
    rowBlock = blockIdx.x << 7;
  }
  const unsigned char* P1b = (const unsigned char*)((MODE == 3 && !isNode) ? P1B : P1);
  const unsigned char* P2b = (const unsigned char*)((MODE == 3 && !isNode) ? P2B : P2);
  const float* b1s = (MODE == 3 && !isNode) ? b1B : b1;
  const float* b2s = (MODE == 3 && !isNode) ? b2B : b2;

  int grow = rowBlock + wid * 32 + l31;
  if (grow >= nr) grow = nr - 1;

  const unsigned short *pS = nullptr, *pR = nullptr, *pE = nullptr;
  const unsigned short *pX = nullptr, *pAg = nullptr;
  const float* fb = nullptr;
  if constexpr (MODE == 0 || MODE == 3) {
    fb = fsrc + (size_t)grow * KIN;
  } else if constexpr (MODE == 1) {
    pS = xb + (size_t)senders[grow] * 128;     // ssend (sorted order)
    pR = xb + (size_t)receivers[grow] * 128;   // srecv (non-decreasing)
    pE = ebuf + (size_t)grow * 128;            // contiguous sorted e
  } else {
    pX  = xb + (size_t)grow * 128;
    pAg = aggb + (size_t)grow * 128;
  }

  auto STG1 = [&](int s) {
    unsigned char* bW = lds + (s & 3) * 16384;
#pragma unroll
    for (int c = 0; c < 4; ++c)
      gll16(P1b + (size_t)s * 16384 + c * 4096 + tid * 16,
            bW + c * 4096 + wid * 1024);
  };
  auto STG2 = [&](int c) {
    unsigned char* bW = lds + ((c + NS1) & 3) * 16384;
#pragma unroll
    for (int q = 0; q < 4; ++q)
      gll16(P2b + (size_t)c * 8192 * 2 + q * 4096 + tid * 16,
            bW + q * 4096 + wid * 1024);
  };

  auto LROW = [&](int s, us8* o) {
    const int k0s = s * 32;
    const unsigned short* p;
    if constexpr (MODE == 1) {
      const int seg = k0s >> 7;
      p = (seg == 0) ? pS : (seg == 1) ? pR : pE;
    } else {
      p = (k0s >> 7) ? pAg : pX;
    }
    const int ko = k0s & 127;
    o[0] = *(const us8*)(p + ko + g * 8);
    o[1] = *(const us8*)(p + ko + 16 + g * 8);
  };
  auto LROWF = [&](int s, f32x4v* rf) {
    const float* p = fb + s * 32 + g * 8;
    rf[0] = *(const f32x4v*)(p);
    rf[1] = *(const f32x4v*)(p + 4);
    rf[2] = *(const f32x4v*)(p + 16);
    rf[3] = *(const f32x4v*)(p + 20);
  };
  auto MKBR = [&](const f32x4v* rf, bf16x8& b0v, bf16x8& b1v) {
    us8 h0, h1;
#pragma unroll
    for (int e = 0; e < 4; ++e) {
      h0[e] = cvt_bf16(rf[0][e]); h0[4 + e] = cvt_bf16(rf[1][e]);
      h1[e] = cvt_bf16(rf[2][e]); h1[4 + e] = cvt_bf16(rf[3][e]);
    }
    b0v = __builtin_bit_cast(bf16x8, h0);
    b1v = __builtin_bit_cast(bf16x8, h1);
  };

  // ================= layer 1 =================
  f32x16 acc1[8];
#pragma unroll
  for (int t = 0; t < 8; ++t)
#pragma unroll
    for (int k = 0; k < 16; ++k) acc1[t][k] = 0.0f;

  auto COMPUTE = [&](const unsigned char* bW, bf16x8 b0v, bf16x8 b1v) {
#pragma unroll
    for (int kc = 0; kc < 2; ++kc) {
      const bf16x8 bv = kc ? b1v : b0v;
#pragma unroll
      for (int nt = 0; nt < 8; ++nt) {
        bf16x8 av = __builtin_bit_cast(bf16x8,
            *(const us8*)(bW + (kc * 8 + nt) * 1024 + lane * 16));
        acc1[nt] = __builtin_amdgcn_mfma_f32_32x32x16_bf16(av, bv, acc1[nt], 0, 0, 0);
      }
    }
  };

  constexpr bool F32IN = (MODE == 0 || MODE == 3);
  us8    rr[4][2];   // 4-slot row rotation (compile-time indexed)
  f32x4v rf[4][4];   // f32-input modes

  STG1(0); STG1(1);
  if constexpr (F32IN) { LROWF(0, rf[0]); LROWF(1, rf[1]); LROWF(2, rf[2]); LROWF(3, rf[3]); }
  else                 { LROW(0, rr[0]);  LROW(1, rr[1]);  LROW(2, rr[2]);  LROW(3, rr[3]); }

#pragma unroll
  for (int p = 0; p < NP; ++p) {
    const int s0 = 2 * p, s1 = 2 * p + 1;
    const int w = (p + 1 < NP) ? (F32IN ? 8 : 4) : 0;
    WAITV(w);
    asm volatile("s_waitcnt lgkmcnt(0)" ::: "memory");
    asm volatile("s_barrier" ::: "memory");

    // consume rows into locals FIRST (R10 WAR fix), then issue next-phase VMEM
    bf16x8 a0v, a1v, c0v, c1v;
    if constexpr (F32IN) { MKBR(rf[s0 & 3], a0v, a1v); MKBR(rf[s1 & 3], c0v, c1v); }
    else {
      a0v = __builtin_bit_cast(bf16x8, rr[s0 & 3][0]); a1v = __builtin_bit_cast(bf16x8, rr[s0 & 3][1]);
      c0v = __builtin_bit_cast(bf16x8, rr[s1 & 3][0]); c1v = __builtin_bit_cast(bf16x8, rr[s1 & 3][1]);
    }

    if (p + 1 < NP) {
      STG1(s0 + 2); STG1(s1 + 2);
      if (p + 2 < NP) {
        if constexpr (F32IN) { LROWF(s0 + 4, rf[(s0 + 4) & 3]); LROWF(s1 + 4, rf[(s1 + 4) & 3]); }
        else                 { LROW(s0 + 4, rr[(s0 + 4) & 3]);  LROW(s1 + 4, rr[(s1 + 4) & 3]); }
      }
    }

    __builtin_amdgcn_s_setprio(1);
    COMPUTE(lds + (s0 & 3) * 16384, a0v, a1v);
    COMPUTE(lds + (s1 & 3) * 16384, c0v, c1v);
    __builtin_amdgcn_s_setprio(0);
  }

  // W2 chunks 0,1 -> bufs (NS1)&3,(NS1+1)&3: distinct from the two bufs the
  // final L1 phase read -> safe without a barrier.
  STG2(0);
  STG2(1);

  // ===== epilogue 1: bias+relu+cvt -> sigma-order A-frags (registers) =====
  u32x4 pa4[16];
#pragma unroll
  for (int t = 0; t < 8; ++t) {
#pragma unroll
    for (int q4 = 0; q4 < 4; ++q4) {
      const f32x4v bv4 = *(const f32x4v*)(b1s + t * 32 + q4 * 8 + g * 4);
      float v0 = fmaxf(acc1[t][q4 * 4 + 0] + bv4[0], 0.0f);
      float v1 = fmaxf(acc1[t][q4 * 4 + 1] + bv4[1], 0.0f);
      float v2 = fmaxf(acc1[t][q4 * 4 + 2] + bv4[2], 0.0f);
      float v3 = fmaxf(acc1[t][q4 * 4 + 3] + bv4[3], 0.0f);
      uint32_t lo, hi;
      asm("v_cvt_pk_bf16_f32 %0, %1, %2" : "=v"(lo) : "v"(v0), "v"(v1));
      asm("v_cvt_pk_bf16_f32 %0, %1, %2" : "=v"(hi) : "v"(v2), "v"(v3));
      pa4[t * 2 + (q4 >> 1)][(q4 & 1) * 2 + 0] = lo;
      pa4[t * 2 + (q4 >> 1)][(q4 & 1) * 2 + 1] = hi;
    }
  }

  // ================= layer 2: 2 chunk-pair phases =================
  f32x16 acc2[4];
#pragma unroll
  for (int nt = 0; nt < 4; ++nt)
#pragma unroll
    for (int k = 0; k < 16; ++k) acc2[nt][k] = 0.0f;

#pragma unroll
  for (int q = 0; q < 2; ++q) {
    WAITV(0);
    asm volatile("s_waitcnt lgkmcnt(0)" ::: "memory");
    asm volatile("s_barrier" ::: "memory");
    if (q == 0) { STG2(2); STG2(3); }   // bufs freed by the q0 barrier
    __builtin_amdgcn_s_setprio(1);
#pragma unroll
    for (int ci = 0; ci < 2; ++ci) {
      const int c = q * 2 + ci;
      const unsigned char* bW = lds + ((c + NS1) & 3) * 16384;
#pragma unroll
      for (int kk = 0; kk < 4; ++kk) {
        const bf16x8 a2 = __builtin_bit_cast(bf16x8, pa4[c * 4 + kk]);
#pragma unroll
        for (int nt = 0; nt < 4; ++nt) {
          const bf16x8 bw = __builtin_bit_cast(bf16x8,
              *(const us8*)(bW + (kk * 4 + nt) * 1024 + lane * 16));
          acc2[nt] = __builtin_amdgcn_mfma_f32_32x32x16_bf16(a2, bw, acc2[nt], 0, 0, 0);
        }
      }
    }
    __builtin_amdgcn_s_setprio(0);
  }

  // ===== epilogue 2: bias+relu, bf16 stores (perm scatter), fused pool =====
  float bias2[4];
#pragma unroll
  for (int nt = 0; nt < 4; ++nt) bias2[nt] = b2s[nt * 32 + l31];

#pragma unroll
  for (int reg = 0; reg < 16; ++reg) {
    const int rowpat = (reg & 3) + ((reg >> 2) << 3) + g * 4;
    const int row = rowBlock + wid * 32 + rowpat;
    const bool ok = (row < nr);
    size_t drow = 0;
    if (ok) drow = (size_t)(((MODE == 0 || MODE == 3) && permsel) ? permsel[row] : row);
    float vs = 0.0f;
#pragma unroll
    for (int nt = 0; nt < 4; ++nt) {
      float v = fmaxf(acc2[nt][reg] + bias2[nt], 0.0f);
      vs += v;
      if (ok) dsel[drow * 128 + nt * 32 + l31] = cvt_bf16(v);
    }
    if constexpr (POOL) {
#pragma unroll
      for (int m = 1; m <= 16; m <<= 1) vs += __shfl_xor(vs, m, 64);
      if (l31 == 0 && ok) pool_out[row] = vs;
    }
  }
}

// ---------------------------------------------------------------------------
// Workspace layout (bytes)
// ---------------------------------------------------------------------------
static constexpr size_t OFF_X    = 0;                          // N*128*2
static constexpr size_t OFF_E    = 5120000;                    // E*128*2 (sorted)
static constexpr size_t OFF_AGG  = 87040000;                   // N*128*2
static constexpr size_t OFF_PN1  = 92160000;
static constexpr size_t OFF_PN2  = OFF_PN1 + 65536;
static constexpr size_t OFF_PE1  = OFF_PN2 + 65536;
static constexpr size_t OFF_PE2  = OFF_PE1 + 65536;
static constexpr size_t OFF_PD1  = OFF_PE2 + 65536;            // 196608
static constexpr size_t OFF_PD2  = OFF_PD1 + 196608;
static constexpr size_t OFF_PM1  = OFF_PD2 + 65536;            // 131072
static constexpr size_t OFF_PM2  = OFF_PM1 + 131072;
static constexpr size_t OFF_CNT  = OFF_PM2 + 65536;            // N*4
static constexpr size_t OFF_OFFS = OFF_CNT + 80000;            // (N+1)*4
static constexpr size_t OFF_CUR  = OFF_OFFS + 80004;           // N*4
static constexpr size_t OFF_POS  = OFF_CUR + 80000;            // E*4
static constexpr size_t OFF_SSEND= OFF_POS + 1280000;          // E*4
static constexpr size_t OFF_SREC = OFF_SSEND + 1280000;        // E*4

extern "C" void kernel_launch(void* const* d_in, const int* in_sizes, int n_in,
                              void* d_out, int out_size, void* d_ws, size_t ws_size,
                              hipStream_t stream) {
  const float* nodes = (const float*)d_in[0];
  const float* edges = (const float*)d_in[1];
  const int* senders = (const int*)d_in[2];
  const int* receivers = (const int*)d_in[3];
  const float* Wn1 = (const float*)d_in[4];  const float* bn1 = (const float*)d_in[5];
  const float* Wn2 = (const float*)d_in[6];  const float* bn2 = (const float*)d_in[7];
  const float* We1 = (const float*)d_in[8];  const float* be1 = (const float*)d_in[9];
  const float* We2 = (const float*)d_in[10]; const float* be2 = (const float*)d_in[11];
  const float* Wed1 = (const float*)d_in[12]; const float* bed1 = (const float*)d_in[13];
  const float* Wed2 = (const float*)d_in[14]; const float* bed2 = (const float*)d_in[15];
  const float* Wnd1 = (const float*)d_in[16]; const float* bnd1 = (const float*)d_in[17];
  const float* Wnd2 = (const float*)d_in[18]; const float* bnd2 = (const float*)d_in[19];

  char* ws = (char*)d_ws;
  unsigned short* xb   = (unsigned short*)(ws + OFF_X);
  unsigned short* eb   = (unsigned short*)(ws + OFF_E);
  unsigned short* aggb = (unsigned short*)(ws + OFF_AGG);
  unsigned short* Pn1  = (unsigned short*)(ws + OFF_PN1);
  unsigned short* Pn2  = (unsigned short*)(ws + OFF_PN2);
  unsigned short* Pe1  = (unsigned short*)(ws + OFF_PE1);
  unsigned short* Pe2  = (unsigned short*)(ws + OFF_PE2);
  unsigned short* Pd1  = (unsigned short*)(ws + OFF_PD1);
  unsigned short* Pd2  = (unsigned short*)(ws + OFF_PD2);
  unsigned short* Pm1  = (unsigned short*)(ws + OFF_PM1);
  unsigned short* Pm2  = (unsigned short*)(ws + OFF_PM2);
  int* cnt    = (int*)(ws + OFF_CNT);
  int* offs   = (int*)(ws + OFF_OFFS);
  int* cursor = (int*)(ws + OFF_CUR);
  int* pos    = (int*)(ws + OFF_POS);
  int* ssend  = (int*)(ws + OFF_SSEND);
  int* srecv  = (int*)(ws + OFF_SREC);
  float* outp = (float*)d_out;

  // all 8 weight packs + receiver histogram in ONE launch
  hipMemsetAsync(cnt, 0, (size_t)N_NODES * 4, stream);
  pack_all<<<2658, 256, 0, stream>>>(Wn1, Wn2, We1, We2, Wed1, Wed2, Wnd1, Wnd2,
                                     Pn1, Pn2, Pe1, Pe2, Pd1, Pd2, Pm1, Pm2,
                                     receivers, cnt);
  scan_k<<<1, 1024, 0, stream>>>(cnt, offs, cursor, N_NODES);
  fill_k<<<1250, 256, 0, stream>>>(senders, receivers, cursor, pos, ssend, srecv, N_EDGES);

  // DUAL embed: node blocks [0,157) + edge blocks [157,2657) in one launch
  mlp_kernel<128, 3, 0><<<NODE_BLOCKS + EDGE_BLOCKS, 256, 0, stream>>>(
      nodes, nullptr, nullptr, nullptr, nullptr, nullptr, pos,
      Pn1, bn1, Pn2, bn2, xb, nullptr, N_NODES,
      edges, Pe1, be1, Pe2, be2, eb);

  for (int it = 0; it < 2; ++it) {
    // edge-model in receiver-sorted order: e contiguous in+out, x gathered
    mlp_kernel<384, 1, 0><<<EDGE_BLOCKS, 256, 0, stream>>>(
        nullptr, xb, eb, nullptr, ssend, srecv, nullptr,
        Pd1, bed1, Pd2, bed2, eb, nullptr, N_EDGES);
    agg_k<<<(N_NODES + 3) / 4, 256, 0, stream>>>(eb, offs, aggb, N_NODES);
    mlp_kernel<256, 2, 1><<<NODE_BLOCKS, 256, 0, stream>>>(
        nullptr, xb, nullptr, aggb, nullptr, nullptr, nullptr,
        Pm1, bnd1, Pm2, bnd2, xb, outp + (size_t)it * N_NODES, N_NODES);
  }
}

// Round 18
// 459.478 us; speedup vs baseline: 1.0983x; 1.0380x over previous
//
#include <hip/hip_runtime.h>
#include <stdint.h>

#define N_NODES 20000
#define N_EDGES 320000
#define NODE_BLOCKS 157   // (N_NODES+127)/128
#define EDGE_BLOCKS 2500  // N_EDGES/128

typedef __attribute__((ext_vector_type(8)))  __bf16        bf16x8;
typedef __attribute__((ext_vector_type(16))) float         f32x16;
typedef __attribute__((ext_vector_type(4)))  float         f32x4v;
typedef __attribute__((ext_vector_type(4)))  uint32_t      u32x4;
typedef __attribute__((ext_vector_type(8)))  unsigned short us8;
typedef __attribute__((ext_vector_type(2)))  unsigned short us2;

static __device__ __forceinline__ unsigned short cvt_bf16(float f) {
  uint32_t u = __builtin_bit_cast(uint32_t, f);
  u = (u + 0x7fffu + ((u >> 16) & 1u)) >> 16;
  return (unsigned short)u;
}
static __device__ __forceinline__ float cvt_f32(unsigned short h) {
  uint32_t u = ((uint32_t)h) << 16;
  return __builtin_bit_cast(float, u);
}

// async global->LDS, 16B per lane; LDS dest = wave-uniform base (HW adds lane*16)
static __device__ __forceinline__ void gll16(const void* g, void* l) {
  __builtin_amdgcn_global_load_lds(
      (const __attribute__((address_space(1))) unsigned int*)g,
      (__attribute__((address_space(3))) unsigned int*)l, 16, 0, 0);
}

// literal-folded counted vmcnt wait (indices constant after full unroll)
#define WAITV(n) do { \
  if ((n) == 0)      asm volatile("s_waitcnt vmcnt(0)" ::: "memory"); \
  else if ((n) == 4) asm volatile("s_waitcnt vmcnt(4)" ::: "memory"); \
  else if ((n) == 8) asm volatile("s_waitcnt vmcnt(8)" ::: "memory"); \
  else               asm volatile("s_waitcnt vmcnt(12)" ::: "memory"); \
} while (0)

// ---------------------------------------------------------------------------
// Weight packing (verified R1-R17) + hist, fused into ONE launch.
// ---------------------------------------------------------------------------
static __device__ __forceinline__ void pw_body(const float* __restrict__ W,
                                               unsigned short* __restrict__ out,
                                               int Ncols, int idx) {
  int e    = idx & 7;
  int lane = (idx >> 3) & 63;
  int t    = idx >> 9;
  int ntiles = Ncols >> 5;
  int nt = t % ntiles;
  int ks = t / ntiles;
  int k = ks * 16 + (lane >> 5) * 8 + e;
  int c = nt * 32 + (lane & 31);
  out[idx] = cvt_bf16(W[(size_t)k * Ncols + c]);
}
static __device__ __forceinline__ void pw2_body(const float* __restrict__ W,
                                                unsigned short* __restrict__ out,
                                                int idx) {
  int e    = idx & 7;
  int lane = (idx >> 3) & 63;
  int t    = idx >> 9;
  int nt = t & 3, ks = t >> 2;
  int k = ks * 16 + ((lane >> 5) << 2) + (e & 3) + ((e >> 2) << 3);
  int c = nt * 32 + (lane & 31);
  out[idx] = cvt_bf16(W[(size_t)k * 128 + c]);
}

__global__ void pack_all(const float* __restrict__ Wn1, const float* __restrict__ Wn2,
                         const float* __restrict__ We1, const float* __restrict__ We2,
                         const float* __restrict__ Wed1, const float* __restrict__ Wed2,
                         const float* __restrict__ Wnd1, const float* __restrict__ Wnd2,
                         unsigned short* __restrict__ Pn1, unsigned short* __restrict__ Pn2,
                         unsigned short* __restrict__ Pe1, unsigned short* __restrict__ Pe2,
                         unsigned short* __restrict__ Pd1, unsigned short* __restrict__ Pd2,
                         unsigned short* __restrict__ Pm1, unsigned short* __restrict__ Pm2,
                         const int* __restrict__ recv, int* __restrict__ cnt) {
  const int b = blockIdx.x, tid = threadIdx.x;
  if      (b <  128) pw_body(Wn1,  Pn1, 256, (b        ) * 256 + tid);
  else if (b <  256) pw_body(We1,  Pe1, 256, (b -  128) * 256 + tid);
  else if (b <  640) pw_body(Wed1, Pd1, 256, (b -  256) * 256 + tid);
  else if (b <  896) pw_body(Wnd1, Pm1, 256, (b -  640) * 256 + tid);
  else if (b < 1024) pw2_body(Wn2,  Pn2, (b -  896) * 256 + tid);
  else if (b < 1152) pw2_body(We2,  Pe2, (b - 1024) * 256 + tid);
  else if (b < 1280) pw2_body(Wed2, Pd2, (b - 1152) * 256 + tid);
  else if (b < 1408) pw2_body(Wnd2, Pm2, (b - 1280) * 256 + tid);
  else {
    int i = (b - 1408) * 256 + tid;
    if (i < N_EDGES) atomicAdd(&cnt[recv[i]], 1);
  }
}

// ---------------------------------------------------------------------------
// CSR build; fill_k emits pos (edge->sorted slot) + sorted senders/receivers.
// ---------------------------------------------------------------------------
__global__ void scan_k(const int* __restrict__ cnt, int* __restrict__ off,
                       int* __restrict__ cursor, int n) {
  __shared__ int part[1024];
  int t = threadIdx.x;
  int chunk = (n + 1023) / 1024;
  int base = t * chunk;
  int s = 0;
  for (int i = 0; i < chunk; ++i) { int idx = base + i; if (idx < n) s += cnt[idx]; }
  part[t] = s;
  __syncthreads();
  for (int d = 1; d < 1024; d <<= 1) {
    int v = (t >= d) ? part[t - d] : 0;
    __syncthreads();
    part[t] += v;
    __syncthreads();
  }
  int prefix = (t > 0) ? part[t - 1] : 0;
  for (int i = 0; i < chunk; ++i) {
    int idx = base + i;
    if (idx < n) { off[idx] = prefix; cursor[idx] = prefix; prefix += cnt[idx]; }
  }
  if (t == 1023) off[n] = part[1023];
}

__global__ void fill_k(const int* __restrict__ send, const int* __restrict__ recv,
                       int* __restrict__ cursor, int* __restrict__ pos,
                       int* __restrict__ ssend, int* __restrict__ srecv, int n) {
  int i = blockIdx.x * 256 + threadIdx.x;
  if (i < n) {
    int p = atomicAdd(&cursor[recv[i]], 1);
    pos[i] = p;
    ssend[p] = send[i];
    srecv[p] = recv[i];
  }
}

// agg[n][:] = sum of CONTIGUOUS sorted e rows [off[n], off[n+1]).
// R18: 2-way unrolled with 4 independent accumulators (halves the dependent
// add chain, doubles memory-level parallelism).
__global__ void agg_k(const unsigned short* __restrict__ eb, const int* __restrict__ off,
                      unsigned short* __restrict__ aggb, int n) {
  int node = blockIdx.x * 4 + (threadIdx.x >> 6);
  if (node >= n) return;
  int lane = threadIdx.x & 63;
  float a0 = 0.f, a1 = 0.f, a2 = 0.f, a3 = 0.f;
  int s = off[node], t = off[node + 1];
  int q = s;
  for (; q + 1 < t; q += 2) {
    us2 v0 = *(const us2*)(eb + (size_t)q * 128 + lane * 2);
    us2 v1 = *(const us2*)(eb + (size_t)(q + 1) * 128 + lane * 2);
    a0 += cvt_f32(v0[0]); a1 += cvt_f32(v0[1]);
    a2 += cvt_f32(v1[0]); a3 += cvt_f32(v1[1]);
  }
  if (q < t) {
    us2 v0 = *(const us2*)(eb + (size_t)q * 128 + lane * 2);
    a0 += cvt_f32(v0[0]); a1 += cvt_f32(v0[1]);
  }
  us2 r; r[0] = cvt_bf16(a0 + a2); r[1] = cvt_bf16(a1 + a3);
  *(us2*)(aggb + (size_t)node * 128 + lane * 2) = r;
}

// ---------------------------------------------------------------------------
// Fused 2-layer MLP (verified structure R6-R17): out = relu(relu(A@W1+b1)@W2+b2)
// 128 rows/block, 4 waves; wave-tile = FULL 256 hidden x 32 rows.
// L1 flipped; H handoff IN REGISTERS (sigma order). Pipeline = R11/R13/R16.
//  MODE 0: A = srcf f32 (KIN=128); optional perm scatter-write.
//  MODE 1: edge-model in RECEIVER-SORTED order (KIN=384).
//  MODE 2: A = [x, agg] bf16 (KIN=256) + fused pool.
//  MODE 3: DUAL EMBED (KIN=128): blocks [0,NODE_BLOCKS) = node set,
//          rest = edge set (srcf2->dst2 via perm scatter). Wave-uniform select.
// ---------------------------------------------------------------------------
template <int KIN, int MODE, int POOL>
__global__ __launch_bounds__(256, 2)
void mlp_kernel(const float* __restrict__ srcf,
                const unsigned short* __restrict__ xb,
                const unsigned short* __restrict__ ebuf,
                const unsigned short* __restrict__ aggb,
                const int* __restrict__ senders,
                const int* __restrict__ receivers,
                const int* __restrict__ perm,
                const unsigned short* __restrict__ P1,
                const float* __restrict__ b1,
                const unsigned short* __restrict__ P2,
                const float* __restrict__ b2,
                unsigned short* __restrict__ dst,
                float* __restrict__ pool_out,
                int nrows,
                const float* __restrict__ srcf2 = nullptr,
                const unsigned short* __restrict__ P1B = nullptr,
                const float* __restrict__ b1B = nullptr,
                const unsigned short* __restrict__ P2B = nullptr,
                const float* __restrict__ b2B = nullptr,
                unsigned short* __restrict__ dst2 = nullptr) {
  constexpr int NS1 = KIN / 32;                 // 4 / 12 / 8 (even)
  constexpr int NP  = NS1 / 2;                  // phases
  __shared__ __align__(16) unsigned char lds[65536];   // 4 x 16KB rotation

  const int tid  = threadIdx.x;
  const int lane = tid & 63;
  const int wid  = tid >> 6;
  const int g    = lane >> 5;
  const int l31  = lane & 31;

  // MODE 3: wave-uniform set selection
  bool isNode = false;
  int rowBlock, nr = nrows;
  const float* fsrc = srcf;
  const int* permsel = perm;
  unsigned short* dsel = dst;
  if constexpr (MODE == 3) {
    isNode = (blockIdx.x < NODE_BLOCKS);
    if (isNode) {
      rowBlock = blockIdx.x << 7;          nr = N_NODES;
      fsrc = srcf;   permsel = nullptr;    dsel = dst;
    } else {
      rowBlock = (blockIdx.x - NODE_BLOCKS) << 7;  nr = N_EDGES;
      fsrc = srcf2;  permsel = perm;       dsel = dst2;
    }
  } else {
    rowBlock = blockIdx.x << 7;
  }
  const unsigned char* P1b = (const unsigned char*)((MODE == 3 && !isNode) ? P1B : P1);
  const unsigned char* P2b = (const unsigned char*)((MODE == 3 && !isNode) ? P2B : P2);
  const float* b1s = (MODE == 3 && !isNode) ? b1B : b1;
  const float* b2s = (MODE == 3 && !isNode) ? b2B : b2;

  int grow = rowBlock + wid * 32 + l31;
  if (grow >= nr) grow = nr - 1;

  const unsigned short *pS = nullptr, *pR = nullptr, *pE = nullptr;
  const unsigned short *pX = nullptr, *pAg = nullptr;
  const float* fb = nullptr;
  if constexpr (MODE == 0 || MODE == 3) {
    fb = fsrc + (size_t)grow * KIN;
  } else if constexpr (MODE == 1) {
    pS = xb + (size_t)senders[grow] * 128;     // ssend (sorted order)
    pR = xb + (size_t)receivers[grow] * 128;   // srecv (non-decreasing)
    pE = ebuf + (size_t)grow * 128;            // contiguous sorted e
  } else {
    pX  = xb + (size_t)grow * 128;
    pAg = aggb + (size_t)grow * 128;
  }

  auto STG1 = [&](int s) {
    unsigned char* bW = lds + (s & 3) * 16384;
#pragma unroll
    for (int c = 0; c < 4; ++c)
      gll16(P1b + (size_t)s * 16384 + c * 4096 + tid * 16,
            bW + c * 4096 + wid * 1024);
  };
  auto STG2 = [&](int c) {
    unsigned char* bW = lds + ((c + NS1) & 3) * 16384;
#pragma unroll
    for (int q = 0; q < 4; ++q)
      gll16(P2b + (size_t)c * 16384 + q * 4096 + tid * 16,
            bW + q * 4096 + wid * 1024);
  };

  auto LROW = [&](int s, us8* o) {
    const int k0s = s * 32;
    const unsigned short* p;
    if constexpr (MODE == 1) {
      const int seg = k0s >> 7;
      p = (seg == 0) ? pS : (seg == 1) ? pR : pE;
    } else {
      p = (k0s >> 7) ? pAg : pX;
    }
    const int ko = k0s & 127;
    o[0] = *(const us8*)(p + ko + g * 8);
    o[1] = *(const us8*)(p + ko + 16 + g * 8);
  };
  auto LROWF = [&](int s, f32x4v* rf) {
    const float* p = fb + s * 32 + g * 8;
    rf[0] = *(const f32x4v*)(p);
    rf[1] = *(const f32x4v*)(p + 4);
    rf[2] = *(const f32x4v*)(p + 16);
    rf[3] = *(const f32x4v*)(p + 20);
  };
  auto MKBR = [&](const f32x4v* rf, bf16x8& b0v, bf16x8& b1v) {
    us8 h0, h1;
#pragma unroll
    for (int e = 0; e < 4; ++e) {
      h0[e] = cvt_bf16(rf[0][e]); h0[4 + e] = cvt_bf16(rf[1][e]);
      h1[e] = cvt_bf16(rf[2][e]); h1[4 + e] = cvt_bf16(rf[3][e]);
    }
    b0v = __builtin_bit_cast(bf16x8, h0);
    b1v = __builtin_bit_cast(bf16x8, h1);
  };

  // ================= layer 1 =================
  f32x16 acc1[8];
#pragma unroll
  for (int t = 0; t < 8; ++t)
#pragma unroll
    for (int k = 0; k < 16; ++k) acc1[t][k] = 0.0f;

  auto COMPUTE = [&](const unsigned char* bW, bf16x8 b0v, bf16x8 b1v) {
#pragma unroll
    for (int kc = 0; kc < 2; ++kc) {
      const bf16x8 bv = kc ? b1v : b0v;
#pragma unroll
      for (int nt = 0; nt < 8; ++nt) {
        bf16x8 av = __builtin_bit_cast(bf16x8,
            *(const us8*)(bW + (kc * 8 + nt) * 1024 + lane * 16));
        acc1[nt] = __builtin_amdgcn_mfma_f32_32x32x16_bf16(av, bv, acc1[nt], 0, 0, 0);
      }
    }
  };

  constexpr bool F32IN = (MODE == 0 || MODE == 3);
  us8    rr[4][2];   // 4-slot row rotation (compile-time indexed)
  f32x4v rf[4][4];   // f32-input modes

  STG1(0); STG1(1);
  if constexpr (F32IN) { LROWF(0, rf[0]); LROWF(1, rf[1]); LROWF(2, rf[2]); LROWF(3, rf[3]); }
  else                 { LROW(0, rr[0]);  LROW(1, rr[1]);  LROW(2, rr[2]);  LROW(3, rr[3]); }

#pragma unroll
  for (int p = 0; p < NP; ++p) {
    const int s0 = 2 * p, s1 = 2 * p + 1;
    const int w = (p + 1 < NP) ? (F32IN ? 8 : 4) : 0;
    WAITV(w);
    asm volatile("s_waitcnt lgkmcnt(0)" ::: "memory");
    asm volatile("s_barrier" ::: "memory");

    // consume rows into locals FIRST (R10 WAR fix), then issue next-phase VMEM
    bf16x8 a0v, a1v, c0v, c1v;
    if constexpr (F32IN) { MKBR(rf[s0 & 3], a0v, a1v); MKBR(rf[s1 & 3], c0v, c1v); }
    else {
      a0v = __builtin_bit_cast(bf16x8, rr[s0 & 3][0]); a1v = __builtin_bit_cast(bf16x8, rr[s0 & 3][1]);
      c0v = __builtin_bit_cast(bf16x8, rr[s1 & 3][0]); c1v = __builtin_bit_cast(bf16x8, rr[s1 & 3][1]);
    }

    if (p + 1 < NP) {
      STG1(s0 + 2); STG1(s1 + 2);
      if (p + 2 < NP) {
        if constexpr (F32IN) { LROWF(s0 + 4, rf[(s0 + 4) & 3]); LROWF(s1 + 4, rf[(s1 + 4) & 3]); }
        else                 { LROW(s0 + 4, rr[(s0 + 4) & 3]);  LROW(s1 + 4, rr[(s1 + 4) & 3]); }
      }
    }

    __builtin_amdgcn_s_setprio(1);
    COMPUTE(lds + (s0 & 3) * 16384, a0v, a1v);
    COMPUTE(lds + (s1 & 3) * 16384, c0v, c1v);
    __builtin_amdgcn_s_setprio(0);
  }

  // W2 chunks 0,1 -> bufs (NS1)&3,(NS1+1)&3: distinct from the two bufs the
  // final L1 phase read -> safe without a barrier.
  STG2(0);
  STG2(1);

  // ===== epilogue 1: bias+relu+cvt -> sigma-order A-frags (registers) =====
  u32x4 pa4[16];
#pragma unroll
  for (int t = 0; t < 8; ++t) {
#pragma unroll
    for (int q4 = 0; q4 < 4; ++q4) {
      const f32x4v bv4 = *(const f32x4v*)(b1s + t * 32 + q4 * 8 + g * 4);
      float v0 = fmaxf(acc1[t][q4 * 4 + 0] + bv4[0], 0.0f);
      float v1 = fmaxf(acc1[t][q4 * 4 + 1] + bv4[1], 0.0f);
      float v2 = fmaxf(acc1[t][q4 * 4 + 2] + bv4[2], 0.0f);
      float v3 = fmaxf(acc1[t][q4 * 4 + 3] + bv4[3], 0.0f);
      uint32_t lo, hi;
      asm("v_cvt_pk_bf16_f32 %0, %1, %2" : "=v"(lo) : "v"(v0), "v"(v1));
      asm("v_cvt_pk_bf16_f32 %0, %1, %2" : "=v"(hi) : "v"(v2), "v"(v3));
      pa4[t * 2 + (q4 >> 1)][(q4 & 1) * 2 + 0] = lo;
      pa4[t * 2 + (q4 >> 1)][(q4 & 1) * 2 + 1] = hi;
    }
  }

  // ================= layer 2: 2 chunk-pair phases =================
  f32x16 acc2[4];
#pragma unroll
  for (int nt = 0; nt < 4; ++nt)
#pragma unroll
    for (int k = 0; k < 16; ++k) acc2[nt][k] = 0.0f;

#pragma unroll
  for (int q = 0; q < 2; ++q) {
    WAITV(0);
    asm volatile("s_waitcnt lgkmcnt(0)" ::: "memory");
    asm volatile("s_barrier" ::: "memory");
    if (q == 0) { STG2(2); STG2(3); }   // bufs freed by the q0 barrier
    __builtin_amdgcn_s_setprio(1);
#pragma unroll
    for (int ci = 0; ci < 2; ++ci) {
      const int c = q * 2 + ci;
      const unsigned char* bW = lds + ((c + NS1) & 3) * 16384;
#pragma unroll
      for (int kk = 0; kk < 4; ++kk) {
        const bf16x8 a2 = __builtin_bit_cast(bf16x8, pa4[c * 4 + kk]);
#pragma unroll
        for (int nt = 0; nt < 4; ++nt) {
          const bf16x8 bw = __builtin_bit_cast(bf16x8,
              *(const us8*)(bW + (kk * 4 + nt) * 1024 + lane * 16));
          acc2[nt] = __builtin_amdgcn_mfma_f32_32x32x16_bf16(a2, bw, acc2[nt], 0, 0, 0);
        }
      }
    }
    __builtin_amdgcn_s_setprio(0);
  }

  // ===== epilogue 2: bias+relu, bf16 stores (perm scatter), fused pool =====
  float bias2[4];
#pragma unroll
  for (int nt = 0; nt < 4; ++nt) bias2[nt] = b2s[nt * 32 + l31];

#pragma unroll
  for (int reg = 0; reg < 16; ++reg) {
    const int rowpat = (reg & 3) + ((reg >> 2) << 3) + g * 4;
    const int row = rowBlock + wid * 32 + rowpat;
    const bool ok = (row < nr);
    size_t drow = 0;
    if (ok) drow = (size_t)(((MODE == 0 || MODE == 3) && permsel) ? permsel[row] : row);
    float vs = 0.0f;
#pragma unroll
    for (int nt = 0; nt < 4; ++nt) {
      float v = fmaxf(acc2[nt][reg] + bias2[nt], 0.0f);
      vs += v;
      if (ok) dsel[drow * 128 + nt * 32 + l31] = cvt_bf16(v);
    }
    if constexpr (POOL) {
#pragma unroll
      for (int m = 1; m <= 16; m <<= 1) vs += __shfl_xor(vs, m, 64);
      if (l31 == 0 && ok) pool_out[row] = vs;
    }
  }
}

// ---------------------------------------------------------------------------
// Workspace layout (bytes)
// ---------------------------------------------------------------------------
static constexpr size_t OFF_X    = 0;                          // N*128*2
static constexpr size_t OFF_E    = 5120000;                    // E*128*2 (sorted)
static constexpr size_t OFF_AGG  = 87040000;                   // N*128*2
static constexpr size_t OFF_PN1  = 92160000;
static constexpr size_t OFF_PN2  = OFF_PN1 + 65536;
static constexpr size_t OFF_PE1  = OFF_PN2 + 65536;
static constexpr size_t OFF_PE2  = OFF_PE1 + 65536;
static constexpr size_t OFF_PD1  = OFF_PE2 + 65536;            // 196608
static constexpr size_t OFF_PD2  = OFF_PD1 + 196608;
static constexpr size_t OFF_PM1  = OFF_PD2 + 65536;            // 131072
static constexpr size_t OFF_PM2  = OFF_PM1 + 131072;
static constexpr size_t OFF_CNT  = OFF_PM2 + 65536;            // N*4
static constexpr size_t OFF_OFFS = OFF_CNT + 80000;            // (N+1)*4
static constexpr size_t OFF_CUR  = OFF_OFFS + 80004;           // N*4
static constexpr size_t OFF_POS  = OFF_CUR + 80000;            // E*4
static constexpr size_t OFF_SSEND= OFF_POS + 1280000;          // E*4
static constexpr size_t OFF_SREC = OFF_SSEND + 1280000;        // E*4

extern "C" void kernel_launch(void* const* d_in, const int* in_sizes, int n_in,
                              void* d_out, int out_size, void* d_ws, size_t ws_size,
                              hipStream_t stream) {
  const float* nodes = (const float*)d_in[0];
  const float* edges = (const float*)d_in[1];
  const int* senders = (const int*)d_in[2];
  const int* receivers = (const int*)d_in[3];
  const float* Wn1 = (const float*)d_in[4];  const float* bn1 = (const float*)d_in[5];
  const float* Wn2 = (const float*)d_in[6];  const float* bn2 = (const float*)d_in[7];
  const float* We1 = (const float*)d_in[8];  const float* be1 = (const float*)d_in[9];
  const float* We2 = (const float*)d_in[10]; const float* be2 = (const float*)d_in[11];
  const float* Wed1 = (const float*)d_in[12]; const float* bed1 = (const float*)d_in[13];
  const float* Wed2 = (const float*)d_in[14]; const float* bed2 = (const float*)d_in[15];
  const float* Wnd1 = (const float*)d_in[16]; const float* bnd1 = (const float*)d_in[17];
  const float* Wnd2 = (const float*)d_in[18]; const float* bnd2 = (const float*)d_in[19];

  char* ws = (char*)d_ws;
  unsigned short* xb   = (unsigned short*)(ws + OFF_X);
  unsigned short* eb   = (unsigned short*)(ws + OFF_E);
  unsigned short* aggb = (unsigned short*)(ws + OFF_AGG);
  unsigned short* Pn1  = (unsigned short*)(ws + OFF_PN1);
  unsigned short* Pn2  = (unsigned short*)(ws + OFF_PN2);
  unsigned short* Pe1  = (unsigned short*)(ws + OFF_PE1);
  unsigned short* Pe2  = (unsigned short*)(ws + OFF_PE2);
  unsigned short* Pd1  = (unsigned short*)(ws + OFF_PD1);
  unsigned short* Pd2  = (unsigned short*)(ws + OFF_PD2);
  unsigned short* Pm1  = (unsigned short*)(ws + OFF_PM1);
  unsigned short* Pm2  = (unsigned short*)(ws + OFF_PM2);
  int* cnt    = (int*)(ws + OFF_CNT);
  int* offs   = (int*)(ws + OFF_OFFS);
  int* cursor = (int*)(ws + OFF_CUR);
  int* pos    = (int*)(ws + OFF_POS);
  int* ssend  = (int*)(ws + OFF_SSEND);
  int* srecv  = (int*)(ws + OFF_SREC);
  float* outp = (float*)d_out;

  // all 8 weight packs + receiver histogram in ONE launch
  hipMemsetAsync(cnt, 0, (size_t)N_NODES * 4, stream);
  pack_all<<<2658, 256, 0, stream>>>(Wn1, Wn2, We1, We2, Wed1, Wed2, Wnd1, Wnd2,
                                     Pn1, Pn2, Pe1, Pe2, Pd1, Pd2, Pm1, Pm2,
                                     receivers, cnt);
  scan_k<<<1, 1024, 0, stream>>>(cnt, offs, cursor, N_NODES);
  fill_k<<<1250, 256, 0, stream>>>(senders, receivers, cursor, pos, ssend, srecv, N_EDGES);

  // DUAL embed: node blocks [0,157) + edge blocks [157,2657) in one launch
  mlp_kernel<128, 3, 0><<<NODE_BLOCKS + EDGE_BLOCKS, 256, 0, stream>>>(
      nodes, nullptr, nullptr, nullptr, nullptr, nullptr, pos,
      Pn1, bn1, Pn2, bn2, xb, nullptr, N_NODES,
      edges, Pe1, be1, Pe2, be2, eb);

  for (int it = 0; it < 2; ++it) {
    // edge-model in receiver-sorted order: e contiguous in+out, x gathered
    mlp_kernel<384, 1, 0><<<EDGE_BLOCKS, 256, 0, stream>>>(
        nullptr, xb, eb, nullptr, ssend, srecv, nullptr,
        Pd1, bed1, Pd2, bed2, eb, nullptr, N_EDGES);
    agg_k<<<(N_NODES + 3) / 4, 256, 0, stream>>>(eb, offs, aggb, N_NODES);
    mlp_kernel<256, 2, 1><<<NODE_BLOCKS, 256, 0, stream>>>(
        nullptr, xb, nullptr, aggb, nullptr, nullptr, nullptr,
        Pm1, bnd1, Pm2, bnd2, xb, outp + (size_t)it * N_NODES, N_NODES);
  }
}

// Round 19
// 454.409 us; speedup vs baseline: 1.1106x; 1.0112x over previous
//
#include <hip/hip_runtime.h>
#include <stdint.h>

#define N_NODES 20000
#define N_EDGES 320000
#define NODE_BLOCKS 157   // (N_NODES+127)/128
#define EDGE_BLOCKS 2500  // N_EDGES/128

typedef __attribute__((ext_vector_type(8)))  __bf16        bf16x8;
typedef __attribute__((ext_vector_type(16))) float         f32x16;
typedef __attribute__((ext_vector_type(4)))  float         f32x4v;
typedef __attribute__((ext_vector_type(4)))  uint32_t      u32x4;
typedef __attribute__((ext_vector_type(8)))  unsigned short us8;
typedef __attribute__((ext_vector_type(2)))  unsigned short us2;

static __device__ __forceinline__ unsigned short cvt_bf16(float f) {
  uint32_t u = __builtin_bit_cast(uint32_t, f);
  u = (u + 0x7fffu + ((u >> 16) & 1u)) >> 16;
  return (unsigned short)u;
}
static __device__ __forceinline__ float cvt_f32(unsigned short h) {
  uint32_t u = ((uint32_t)h) << 16;
  return __builtin_bit_cast(float, u);
}

// async global->LDS, 16B per lane; LDS dest = wave-uniform base (HW adds lane*16)
static __device__ __forceinline__ void gll16(const void* g, void* l) {
  __builtin_amdgcn_global_load_lds(
      (const __attribute__((address_space(1))) unsigned int*)g,
      (__attribute__((address_space(3))) unsigned int*)l, 16, 0, 0);
}

// literal-folded counted vmcnt wait (indices constant after full unroll)
#define WAITV(n) do { \
  if ((n) == 0)      asm volatile("s_waitcnt vmcnt(0)" ::: "memory"); \
  else if ((n) == 4) asm volatile("s_waitcnt vmcnt(4)" ::: "memory"); \
  else if ((n) == 8) asm volatile("s_waitcnt vmcnt(8)" ::: "memory"); \
  else               asm volatile("s_waitcnt vmcnt(12)" ::: "memory"); \
} while (0)

// ---------------------------------------------------------------------------
// Weight packing (verified R1-R18) + hist, fused into ONE launch.
// ---------------------------------------------------------------------------
static __device__ __forceinline__ void pw_body(const float* __restrict__ W,
                                               unsigned short* __restrict__ out,
                                               int Ncols, int idx) {
  int e    = idx & 7;
  int lane = (idx >> 3) & 63;
  int t    = idx >> 9;
  int ntiles = Ncols >> 5;
  int nt = t % ntiles;
  int ks = t / ntiles;
  int k = ks * 16 + (lane >> 5) * 8 + e;
  int c = nt * 32 + (lane & 31);
  out[idx] = cvt_bf16(W[(size_t)k * Ncols + c]);
}
static __device__ __forceinline__ void pw2_body(const float* __restrict__ W,
                                                unsigned short* __restrict__ out,
                                                int idx) {
  int e    = idx & 7;
  int lane = (idx >> 3) & 63;
  int t    = idx >> 9;
  int nt = t & 3, ks = t >> 2;
  int k = ks * 16 + ((lane >> 5) << 2) + (e & 3) + ((e >> 2) << 3);
  int c = nt * 32 + (lane & 31);
  out[idx] = cvt_bf16(W[(size_t)k * 128 + c]);
}

__global__ void pack_all(const float* __restrict__ Wn1, const float* __restrict__ Wn2,
                         const float* __restrict__ We1, const float* __restrict__ We2,
                         const float* __restrict__ Wed1, const float* __restrict__ Wed2,
                         const float* __restrict__ Wnd1, const float* __restrict__ Wnd2,
                         unsigned short* __restrict__ Pn1, unsigned short* __restrict__ Pn2,
                         unsigned short* __restrict__ Pe1, unsigned short* __restrict__ Pe2,
                         unsigned short* __restrict__ Pd1, unsigned short* __restrict__ Pd2,
                         unsigned short* __restrict__ Pm1, unsigned short* __restrict__ Pm2,
                         const int* __restrict__ recv, int* __restrict__ cnt) {
  const int b = blockIdx.x, tid = threadIdx.x;
  if      (b <  128) pw_body(Wn1,  Pn1, 256, (b        ) * 256 + tid);
  else if (b <  256) pw_body(We1,  Pe1, 256, (b -  128) * 256 + tid);
  else if (b <  640) pw_body(Wed1, Pd1, 256, (b -  256) * 256 + tid);
  else if (b <  896) pw_body(Wnd1, Pm1, 256, (b -  640) * 256 + tid);
  else if (b < 1024) pw2_body(Wn2,  Pn2, (b -  896) * 256 + tid);
  else if (b < 1152) pw2_body(We2,  Pe2, (b - 1024) * 256 + tid);
  else if (b < 1280) pw2_body(Wed2, Pd2, (b - 1152) * 256 + tid);
  else if (b < 1408) pw2_body(Wnd2, Pm2, (b - 1280) * 256 + tid);
  else {
    int i = (b - 1408) * 256 + tid;
    if (i < N_EDGES) atomicAdd(&cnt[recv[i]], 1);
  }
}

// ---------------------------------------------------------------------------
// CSR build; fill_k emits pos (edge->sorted slot) + sorted senders/receivers.
// ---------------------------------------------------------------------------
__global__ void scan_k(const int* __restrict__ cnt, int* __restrict__ off,
                       int* __restrict__ cursor, int n) {
  __shared__ int part[1024];
  int t = threadIdx.x;
  int chunk = (n + 1023) / 1024;
  int base = t * chunk;
  int s = 0;
  for (int i = 0; i < chunk; ++i) { int idx = base + i; if (idx < n) s += cnt[idx]; }
  part[t] = s;
  __syncthreads();
  for (int d = 1; d < 1024; d <<= 1) {
    int v = (t >= d) ? part[t - d] : 0;
    __syncthreads();
    part[t] += v;
    __syncthreads();
  }
  int prefix = (t > 0) ? part[t - 1] : 0;
  for (int i = 0; i < chunk; ++i) {
    int idx = base + i;
    if (idx < n) { off[idx] = prefix; cursor[idx] = prefix; prefix += cnt[idx]; }
  }
  if (t == 1023) off[n] = part[1023];
}

__global__ void fill_k(const int* __restrict__ send, const int* __restrict__ recv,
                       int* __restrict__ cursor, int* __restrict__ pos,
                       int* __restrict__ ssend, int* __restrict__ srecv, int n) {
  int i = blockIdx.x * 256 + threadIdx.x;
  if (i < n) {
    int p = atomicAdd(&cursor[recv[i]], 1);
    pos[i] = p;
    ssend[p] = send[i];
    srecv[p] = recv[i];
  }
}

// agg[n][:] = sum of CONTIGUOUS sorted e rows [off[n], off[n+1]).
// R19: 4-way unrolled, 8 independent accumulators (chain/4, 4x MLP);
// 2-way and 1-way tails.
__global__ void agg_k(const unsigned short* __restrict__ eb, const int* __restrict__ off,
                      unsigned short* __restrict__ aggb, int n) {
  int node = blockIdx.x * 4 + (threadIdx.x >> 6);
  if (node >= n) return;
  int lane = threadIdx.x & 63;
  float a0 = 0.f, a1 = 0.f, a2 = 0.f, a3 = 0.f;
  float a4 = 0.f, a5 = 0.f, a6 = 0.f, a7 = 0.f;
  int s = off[node], t = off[node + 1];
  int q = s;
  for (; q + 3 < t; q += 4) {
    us2 v0 = *(const us2*)(eb + (size_t)q * 128 + lane * 2);
    us2 v1 = *(const us2*)(eb + (size_t)(q + 1) * 128 + lane * 2);
    us2 v2 = *(const us2*)(eb + (size_t)(q + 2) * 128 + lane * 2);
    us2 v3 = *(const us2*)(eb + (size_t)(q + 3) * 128 + lane * 2);
    a0 += cvt_f32(v0[0]); a1 += cvt_f32(v0[1]);
    a2 += cvt_f32(v1[0]); a3 += cvt_f32(v1[1]);
    a4 += cvt_f32(v2[0]); a5 += cvt_f32(v2[1]);
    a6 += cvt_f32(v3[0]); a7 += cvt_f32(v3[1]);
  }
  for (; q + 1 < t; q += 2) {
    us2 v0 = *(const us2*)(eb + (size_t)q * 128 + lane * 2);
    us2 v1 = *(const us2*)(eb + (size_t)(q + 1) * 128 + lane * 2);
    a0 += cvt_f32(v0[0]); a1 += cvt_f32(v0[1]);
    a2 += cvt_f32(v1[0]); a3 += cvt_f32(v1[1]);
  }
  if (q < t) {
    us2 v0 = *(const us2*)(eb + (size_t)q * 128 + lane * 2);
    a0 += cvt_f32(v0[0]); a1 += cvt_f32(v0[1]);
  }
  us2 r;
  r[0] = cvt_bf16((a0 + a2) + (a4 + a6));
  r[1] = cvt_bf16((a1 + a3) + (a5 + a7));
  *(us2*)(aggb + (size_t)node * 128 + lane * 2) = r;
}

// ---------------------------------------------------------------------------
// Fused 2-layer MLP (verified structure R6-R18): out = relu(relu(A@W1+b1)@W2+b2)
// 128 rows/block, 4 waves; wave-tile = FULL 256 hidden x 32 rows.
// L1 flipped; H handoff IN REGISTERS (sigma order). Pipeline = R11/R13/R16.
//  MODE 0: A = srcf f32 (KIN=128); optional perm scatter-write.
//  MODE 1: edge-model in RECEIVER-SORTED order (KIN=384).
//  MODE 2: A = [x, agg] bf16 (KIN=256) + fused pool.
//  MODE 3: DUAL EMBED (KIN=128): blocks [0,NODE_BLOCKS) = node set,
//          rest = edge set (srcf2->dst2 via perm scatter). Wave-uniform select.
// ---------------------------------------------------------------------------
template <int KIN, int MODE, int POOL>
__global__ __launch_bounds__(256, 2)
void mlp_kernel(const float* __restrict__ srcf,
                const unsigned short* __restrict__ xb,
                const unsigned short* __restrict__ ebuf,
                const unsigned short* __restrict__ aggb,
                const int* __restrict__ senders,
                const int* __restrict__ receivers,
                const int* __restrict__ perm,
                const unsigned short* __restrict__ P1,
                const float* __restrict__ b1,
                const unsigned short* __restrict__ P2,
                const float* __restrict__ b2,
                unsigned short* __restrict__ dst,
                float* __restrict__ pool_out,
                int nrows,
                const float* __restrict__ srcf2 = nullptr,
                const unsigned short* __restrict__ P1B = nullptr,
                const float* __restrict__ b1B = nullptr,
                const unsigned short* __restrict__ P2B = nullptr,
                const float* __restrict__ b2B = nullptr,
                unsigned short* __restrict__ dst2 = nullptr) {
  constexpr int NS1 = KIN / 32;                 // 4 / 12 / 8 (even)
  constexpr int NP  = NS1 / 2;                  // phases
  __shared__ __align__(16) unsigned char lds[65536];   // 4 x 16KB rotation

  const int tid  = threadIdx.x;
  const int lane = tid & 63;
  const int wid  = tid >> 6;
  const int g    = lane >> 5;
  const int l31  = lane & 31;

  // MODE 3: wave-uniform set selection
  bool isNode = false;
  int rowBlock, nr = nrows;
  const float* fsrc = srcf;
  const int* permsel = perm;
  unsigned short* dsel = dst;
  if constexpr (MODE == 3) {
    isNode = (blockIdx.x < NODE_BLOCKS);
    if (isNode) {
      rowBlock = blockIdx.x << 7;          nr = N_NODES;
      fsrc = srcf;   permsel = nullptr;    dsel = dst;
    } else {
      rowBlock = (blockIdx.x - NODE_BLOCKS) << 7;  nr = N_EDGES;
      fsrc = srcf2;  permsel = perm;       dsel = dst2;
    }
  } else {
    rowBlock = blockIdx.x << 7;
  }
  const unsigned char* P1b = (const unsigned char*)((MODE == 3 && !isNode) ? P1B : P1);
  const unsigned char* P2b = (const unsigned char*)((MODE == 3 && !isNode) ? P2B : P2);
  const float* b1s = (MODE == 3 && !isNode) ? b1B : b1;
  const float* b2s = (MODE == 3 && !isNode) ? b2B : b2;

  int grow = rowBlock + wid * 32 + l31;
  if (grow >= nr) grow = nr - 1;

  const unsigned short *pS = nullptr, *pR = nullptr, *pE = nullptr;
  const unsigned short *pX = nullptr, *pAg = nullptr;
  const float* fb = nullptr;
  if constexpr (MODE == 0 || MODE == 3) {
    fb = fsrc + (size_t)grow * KIN;
  } else if constexpr (MODE == 1) {
    pS = xb + (size_t)senders[grow] * 128;     // ssend (sorted order)
    pR = xb + (size_t)receivers[grow] * 128;   // srecv (non-decreasing)
    pE = ebuf + (size_t)grow * 128;            // contiguous sorted e
  } else {
    pX  = xb + (size_t)grow * 128;
    pAg = aggb + (size_t)grow * 128;
  }

  auto STG1 = [&](int s) {
    unsigned char* bW = lds + (s & 3) * 16384;
#pragma unroll
    for (int c = 0; c < 4; ++c)
      gll16(P1b + (size_t)s * 16384 + c * 4096 + tid * 16,
            bW + c * 4096 + wid * 1024);
  };
  auto STG2 = [&](int c) {
    unsigned char* bW = lds + ((c + NS1) & 3) * 16384;
#pragma unroll
    for (int q = 0; q < 4; ++q)
      gll16(P2b + (size_t)c * 16384 + q * 4096 + tid * 16,
            bW + q * 4096 + wid * 1024);
  };

  auto LROW = [&](int s, us8* o) {
    const int k0s = s * 32;
    const unsigned short* p;
    if constexpr (MODE == 1) {
      const int seg = k0s >> 7;
      p = (seg == 0) ? pS : (seg == 1) ? pR : pE;
    } else {
      p = (k0s >> 7) ? pAg : pX;
    }
    const int ko = k0s & 127;
    o[0] = *(const us8*)(p + ko + g * 8);
    o[1] = *(const us8*)(p + ko + 16 + g * 8);
  };
  auto LROWF = [&](int s, f32x4v* rf) {
    const float* p = fb + s * 32 + g * 8;
    rf[0] = *(const f32x4v*)(p);
    rf[1] = *(const f32x4v*)(p + 4);
    rf[2] = *(const f32x4v*)(p + 16);
    rf[3] = *(const f32x4v*)(p + 20);
  };
  auto MKBR = [&](const f32x4v* rf, bf16x8& b0v, bf16x8& b1v) {
    us8 h0, h1;
#pragma unroll
    for (int e = 0; e < 4; ++e) {
      h0[e] = cvt_bf16(rf[0][e]); h0[4 + e] = cvt_bf16(rf[1][e]);
      h1[e] = cvt_bf16(rf[2][e]); h1[4 + e] = cvt_bf16(rf[3][e]);
    }
    b0v = __builtin_bit_cast(bf16x8, h0);
    b1v = __builtin_bit_cast(bf16x8, h1);
  };

  // ================= layer 1 =================
  f32x16 acc1[8];
#pragma unroll
  for (int t = 0; t < 8; ++t)
#pragma unroll
    for (int k = 0; k < 16; ++k) acc1[t][k] = 0.0f;

  auto COMPUTE = [&](const unsigned char* bW, bf16x8 b0v, bf16x8 b1v) {
#pragma unroll
    for (int kc = 0; kc < 2; ++kc) {
      const bf16x8 bv = kc ? b1v : b0v;
#pragma unroll
      for (int nt = 0; nt < 8; ++nt) {
        bf16x8 av = __builtin_bit_cast(bf16x8,
            *(const us8*)(bW + (kc * 8 + nt) * 1024 + lane * 16));
        acc1[nt] = __builtin_amdgcn_mfma_f32_32x32x16_bf16(av, bv, acc1[nt], 0, 0, 0);
      }
    }
  };

  constexpr bool F32IN = (MODE == 0 || MODE == 3);
  us8    rr[4][2];   // 4-slot row rotation (compile-time indexed)
  f32x4v rf[4][4];   // f32-input modes

  STG1(0); STG1(1);
  if constexpr (F32IN) { LROWF(0, rf[0]); LROWF(1, rf[1]); LROWF(2, rf[2]); LROWF(3, rf[3]); }
  else                 { LROW(0, rr[0]);  LROW(1, rr[1]);  LROW(2, rr[2]);  LROW(3, rr[3]); }

#pragma unroll
  for (int p = 0; p < NP; ++p) {
    const int s0 = 2 * p, s1 = 2 * p + 1;
    const int w = (p + 1 < NP) ? (F32IN ? 8 : 4) : 0;
    WAITV(w);
    asm volatile("s_waitcnt lgkmcnt(0)" ::: "memory");
    asm volatile("s_barrier" ::: "memory");

    // consume rows into locals FIRST (R10 WAR fix), then issue next-phase VMEM
    bf16x8 a0v, a1v, c0v, c1v;
    if constexpr (F32IN) { MKBR(rf[s0 & 3], a0v, a1v); MKBR(rf[s1 & 3], c0v, c1v); }
    else {
      a0v = __builtin_bit_cast(bf16x8, rr[s0 & 3][0]); a1v = __builtin_bit_cast(bf16x8, rr[s0 & 3][1]);
      c0v = __builtin_bit_cast(bf16x8, rr[s1 & 3][0]); c1v = __builtin_bit_cast(bf16x8, rr[s1 & 3][1]);
    }

    if (p + 1 < NP) {
      STG1(s0 + 2); STG1(s1 + 2);
      if (p + 2 < NP) {
        if constexpr (F32IN) { LROWF(s0 + 4, rf[(s0 + 4) & 3]); LROWF(s1 + 4, rf[(s1 + 4) & 3]); }
        else                 { LROW(s0 + 4, rr[(s0 + 4) & 3]);  LROW(s1 + 4, rr[(s1 + 4) & 3]); }
      }
    }

    __builtin_amdgcn_s_setprio(1);
    COMPUTE(lds + (s0 & 3) * 16384, a0v, a1v);
    COMPUTE(lds + (s1 & 3) * 16384, c0v, c1v);
    __builtin_amdgcn_s_setprio(0);
  }

  // W2 chunks 0,1 -> bufs (NS1)&3,(NS1+1)&3: distinct from the two bufs the
  // final L1 phase read -> safe without a barrier.
  STG2(0);
  STG2(1);

  // ===== epilogue 1: bias+relu+cvt -> sigma-order A-frags (registers) =====
  u32x4 pa4[16];
#pragma unroll
  for (int t = 0; t < 8; ++t) {
#pragma unroll
    for (int q4 = 0; q4 < 4; ++q4) {
      const f32x4v bv4 = *(const f32x4v*)(b1s + t * 32 + q4 * 8 + g * 4);
      float v0 = fmaxf(acc1[t][q4 * 4 + 0] + bv4[0], 0.0f);
      float v1 = fmaxf(acc1[t][q4 * 4 + 1] + bv4[1], 0.0f);
      float v2 = fmaxf(acc1[t][q4 * 4 + 2] + bv4[2], 0.0f);
      float v3 = fmaxf(acc1[t][q4 * 4 + 3] + bv4[3], 0.0f);
      uint32_t lo, hi;
      asm("v_cvt_pk_bf16_f32 %0, %1, %2" : "=v"(lo) : "v"(v0), "v"(v1));
      asm("v_cvt_pk_bf16_f32 %0, %1, %2" : "=v"(hi) : "v"(v2), "v"(v3));
      pa4[t * 2 + (q4 >> 1)][(q4 & 1) * 2 + 0] = lo;
      pa4[t * 2 + (q4 >> 1)][(q4 & 1) * 2 + 1] = hi;
    }
  }

  // ================= layer 2: 2 chunk-pair phases =================
  f32x16 acc2[4];
#pragma unroll
  for (int nt = 0; nt < 4; ++nt)
#pragma unroll
    for (int k = 0; k < 16; ++k) acc2[nt][k] = 0.0f;

#pragma unroll
  for (int q = 0; q < 2; ++q) {
    WAITV(0);
    asm volatile("s_waitcnt lgkmcnt(0)" ::: "memory");
    asm volatile("s_barrier" ::: "memory");
    if (q == 0) { STG2(2); STG2(3); }   // bufs freed by the q0 barrier
    __builtin_amdgcn_s_setprio(1);
#pragma unroll
    for (int ci = 0; ci < 2; ++ci) {
      const int c = q * 2 + ci;
      const unsigned char* bW = lds + ((c + NS1) & 3) * 16384;
#pragma unroll
      for (int kk = 0; kk < 4; ++kk) {
        const bf16x8 a2 = __builtin_bit_cast(bf16x8, pa4[c * 4 + kk]);
#pragma unroll
        for (int nt = 0; nt < 4; ++nt) {
          const bf16x8 bw = __builtin_bit_cast(bf16x8,
              *(const us8*)(bW + (kk * 4 + nt) * 1024 + lane * 16));
          acc2[nt] = __builtin_amdgcn_mfma_f32_32x32x16_bf16(a2, bw, acc2[nt], 0, 0, 0);
        }
      }
    }
    __builtin_amdgcn_s_setprio(0);
  }

  // ===== epilogue 2: bias+relu, bf16 stores (perm scatter), fused pool =====
  float bias2[4];
#pragma unroll
  for (int nt = 0; nt < 4; ++nt) bias2[nt] = b2s[nt * 32 + l31];

#pragma unroll
  for (int reg = 0; reg < 16; ++reg) {
    const int rowpat = (reg & 3) + ((reg >> 2) << 3) + g * 4;
    const int row = rowBlock + wid * 32 + rowpat;
    const bool ok = (row < nr);
    size_t drow = 0;
    if (ok) drow = (size_t)(((MODE == 0 || MODE == 3) && permsel) ? permsel[row] : row);
    float vs = 0.0f;
#pragma unroll
    for (int nt = 0; nt < 4; ++nt) {
      float v = fmaxf(acc2[nt][reg] + bias2[nt], 0.0f);
      vs += v;
      if (ok) dsel[drow * 128 + nt * 32 + l31] = cvt_bf16(v);
    }
    if constexpr (POOL) {
#pragma unroll
      for (int m = 1; m <= 16; m <<= 1) vs += __shfl_xor(vs, m, 64);
      if (l31 == 0 && ok) pool_out[row] = vs;
    }
  }
}

// ---------------------------------------------------------------------------
// Workspace layout (bytes)
// ---------------------------------------------------------------------------
static constexpr size_t OFF_X    = 0;                          // N*128*2
static constexpr size_t OFF_E    = 5120000;                    // E*128*2 (sorted)
static constexpr size_t OFF_AGG  = 87040000;                   // N*128*2
static constexpr size_t OFF_PN1  = 92160000;
static constexpr size_t OFF_PN2  = OFF_PN1 + 65536;
static constexpr size_t OFF_PE1  = OFF_PN2 + 65536;
static constexpr size_t OFF_PE2  = OFF_PE1 + 65536;
static constexpr size_t OFF_PD1  = OFF_PE2 + 65536;            // 196608
static constexpr size_t OFF_PD2  = OFF_PD1 + 196608;
static constexpr size_t OFF_PM1  = OFF_PD2 + 65536;            // 131072
static constexpr size_t OFF_PM2  = OFF_PM1 + 131072;
static constexpr size_t OFF_CNT  = OFF_PM2 + 65536;            // N*4
static constexpr size_t OFF_OFFS = OFF_CNT + 80000;            // (N+1)*4
static constexpr size_t OFF_CUR  = OFF_OFFS + 80004;           // N*4
static constexpr size_t OFF_POS  = OFF_CUR + 80000;            // E*4
static constexpr size_t OFF_SSEND= OFF_POS + 1280000;          // E*4
static constexpr size_t OFF_SREC = OFF_SSEND + 1280000;        // E*4

extern "C" void kernel_launch(void* const* d_in, const int* in_sizes, int n_in,
                              void* d_out, int out_size, void* d_ws, size_t ws_size,
                              hipStream_t stream) {
  const float* nodes = (const float*)d_in[0];
  const float* edges = (const float*)d_in[1];
  const int* senders = (const int*)d_in[2];
  const int* receivers = (const int*)d_in[3];
  const float* Wn1 = (const float*)d_in[4];  const float* bn1 = (const float*)d_in[5];
  const float* Wn2 = (const float*)d_in[6];  const float* bn2 = (const float*)d_in[7];
  const float* We1 = (const float*)d_in[8];  const float* be1 = (const float*)d_in[9];
  const float* We2 = (const float*)d_in[10]; const float* be2 = (const float*)d_in[11];
  const float* Wed1 = (const float*)d_in[12]; const float* bed1 = (const float*)d_in[13];
  const float* Wed2 = (const float*)d_in[14]; const float* bed2 = (const float*)d_in[15];
  const float* Wnd1 = (const float*)d_in[16]; const float* bnd1 = (const float*)d_in[17];
  const float* Wnd2 = (const float*)d_in[18]; const float* bnd2 = (const float*)d_in[19];

  char* ws = (char*)d_ws;
  unsigned short* xb   = (unsigned short*)(ws + OFF_X);
  unsigned short* eb   = (unsigned short*)(ws + OFF_E);
  unsigned short* aggb = (unsigned short*)(ws + OFF_AGG);
  unsigned short* Pn1  = (unsigned short*)(ws + OFF_PN1);
  unsigned short* Pn2  = (unsigned short*)(ws + OFF_PN2);
  unsigned short* Pe1  = (unsigned short*)(ws + OFF_PE1);
  unsigned short* Pe2  = (unsigned short*)(ws + OFF_PE2);
  unsigned short* Pd1  = (unsigned short*)(ws + OFF_PD1);
  unsigned short* Pd2  = (unsigned short*)(ws + OFF_PD2);
  unsigned short* Pm1  = (unsigned short*)(ws + OFF_PM1);
  unsigned short* Pm2  = (unsigned short*)(ws + OFF_PM2);
  int* cnt    = (int*)(ws + OFF_CNT);
  int* offs   = (int*)(ws + OFF_OFFS);
  int* cursor = (int*)(ws + OFF_CUR);
  int* pos    = (int*)(ws + OFF_POS);
  int* ssend  = (int*)(ws + OFF_SSEND);
  int* srecv  = (int*)(ws + OFF_SREC);
  float* outp = (float*)d_out;

  // all 8 weight packs + receiver histogram in ONE launch
  hipMemsetAsync(cnt, 0, (size_t)N_NODES * 4, stream);
  pack_all<<<2658, 256, 0, stream>>>(Wn1, Wn2, We1, We2, Wed1, Wed2, Wnd1, Wnd2,
                                     Pn1, Pn2, Pe1, Pe2, Pd1, Pd2, Pm1, Pm2,
                                     receivers, cnt);
  scan_k<<<1, 1024, 0, stream>>>(cnt, offs, cursor, N_NODES);
  fill_k<<<1250, 256, 0, stream>>>(senders, receivers, cursor, pos, ssend, srecv, N_EDGES);

  // DUAL embed: node blocks [0,157) + edge blocks [157,2657) in one launch
  mlp_kernel<128, 3, 0><<<NODE_BLOCKS + EDGE_BLOCKS, 256, 0, stream>>>(
      nodes, nullptr, nullptr, nullptr, nullptr, nullptr, pos,
      Pn1, bn1, Pn2, bn2, xb, nullptr, N_NODES,
      edges, Pe1, be1, Pe2, be2, eb);

  for (int it = 0; it < 2; ++it) {
    // edge-model in receiver-sorted order: e contiguous in+out, x gathered
    mlp_kernel<384, 1, 0><<<EDGE_BLOCKS, 256, 0, stream>>>(
        nullptr, xb, eb, nullptr, ssend, srecv, nullptr,
        Pd1, bed1, Pd2, bed2, eb, nullptr, N_EDGES);
    agg_k<<<(N_NODES + 3) / 4, 256, 0, stream>>>(eb, offs, aggb, N_NODES);
    mlp_kernel<256, 2, 1><<<NODE_BLOCKS, 256, 0, stream>>>(
        nullptr, xb, nullptr, aggb, nullptr, nullptr, nullptr,
        Pm1, bnd1, Pm2, bnd2, xb, outp + (size_t)it * N_NODES, N_NODES);
  }
}